// Round 9
// baseline (248.536 us; speedup 1.0000x reference)
//
#include <hip/hip_runtime.h>
#include <stdint.h>

typedef __attribute__((ext_vector_type(8))) short bf16x8;
typedef __attribute__((ext_vector_type(4))) float f32x4;

#define MFMA16(a, b, c) __builtin_amdgcn_mfma_f32_16x16x32_bf16((a), (b), (c), 0, 0, 0)

#if __has_builtin(__builtin_amdgcn_rcpf)
#define FRCP(x) __builtin_amdgcn_rcpf(x)
#else
#define FRCP(x) (1.0f / (x))
#endif
#if __has_builtin(__builtin_amdgcn_sqrtf)
#define FSQRT(x) __builtin_amdgcn_sqrtf(x)
#else
#define FSQRT(x) sqrtf(x)
#endif
#if __has_builtin(__builtin_amdgcn_rsqf)
#define FRSQ(x) __builtin_amdgcn_rsqf(x)
#else
#define FRSQ(x) (1.0f / FSQRT(x))
#endif

static constexpr int BATCH = 4;
static constexpr int QLEN  = 4096;
static constexpr int KLEN  = 4096;
static constexpr int DDIM  = 64;
static constexpr int VDIM  = 64;
static constexpr float SCALE = 0.125f;           // 1/sqrt(64), folded into Q at preprocess
static constexpr float LOG2E = 1.44269504088896340736f;

__device__ __forceinline__ float bf2f(uint32_t h) {
    union { uint32_t u; float f; } v; v.u = h << 16; return v.f;
}
__device__ __forceinline__ short f2bf(float x) {
    union { float f; uint32_t u; } v; v.f = x;
    uint32_t u = v.u;
    return (short)((u + 0x7fffu + ((u >> 16) & 1u)) >> 16);   // RNE
}
__device__ __forceinline__ bf16x8 neg8(bf16x8 x) {
#pragma unroll
    for (int i = 0; i < 8; ++i) x[i] ^= (short)0x8000;
    return x;
}
// v_cvt_pk_bf16_f32: d.lo = bf16(lo), d.hi = bf16(hi). No builtin on gfx950 -> asm.
__device__ __forceinline__ uint32_t cvt_pk_bf16(float lo, float hi) {
    uint32_t d;
    asm("v_cvt_pk_bf16_f32 %0, %1, %2" : "=v"(d) : "v"(lo), "v"(hi));
    return d;
}
__device__ __forceinline__ bf16x8 mk8(uint32_t a, uint32_t b, uint32_t c, uint32_t d) {
    union { uint32_t u[4]; bf16x8 v; } x;
    x.u[0] = a; x.u[1] = b; x.u[2] = c; x.u[3] = d;
    return x.v;
}
// async global->LDS DMA, 16B per lane. LDS dest = uniform base + lane*16;
// global src is PER-LANE. Counts in vmcnt.
__device__ __forceinline__ void gload16(const void* g, void* l) {
    __builtin_amdgcn_global_load_lds(
        (const __attribute__((address_space(1))) uint32_t*)g,
        (__attribute__((address_space(3))) uint32_t*)l, 16, 0, 0);
}

// Block-uniform dtype detect: bf16-packed u32 pairs vs float2 per element.
__device__ __forceinline__ bool detect_bf(const uint32_t* src, int tid, int nthreads, int* scnt) {
    if (tid == 0) *scnt = 0;
    __syncthreads();
    int local = 0;
    for (int i = tid; i < 1024; i += nthreads) {
        uint32_t e = (src[i] >> 7) & 0xFFu;
        local += (e >= 110u && e <= 135u) ? 1 : 0;
    }
    atomicAdd(scnt, local);
    __syncthreads();
    return *scnt > 512;
}

// ---------- fused preprocess: QK conv (8 elems/thread) + V transpose ----------
// blocks [0, 2*NCV): vectorized elementwise Q (scaled) / K -> bf16 planes
// blocks [2*NCV, +NVT): V [b][k][v] -> VrT/ViT [b][v][k]
__global__ void prep_kernel(const void* __restrict__ qsrc, const void* __restrict__ ksrc,
                            const void* __restrict__ vsrc,
                            uint16_t* __restrict__ Qr, uint16_t* __restrict__ Qi,
                            uint16_t* __restrict__ Kr, uint16_t* __restrict__ Ki,
                            uint16_t* __restrict__ vr, uint16_t* __restrict__ vi, int n) {
    __shared__ int scnt;
    __shared__ uint16_t tr[32][33];
    __shared__ uint16_t ti[32][33];
    const int NCV = n / 2048;             // conv blocks per tensor (8 elems/thread)
    const int tid = threadIdx.x;
    int bid = blockIdx.x;

    if (bid < 2 * NCV) {
        const bool isQ = (bid < NCV);
        const void* src = isQ ? qsrc : ksrc;
        const bool isbf = detect_bf((const uint32_t*)src, tid, 256, &scnt);
        const int i0 = ((isQ ? bid : bid - NCV) * 256 + tid) * 8;
        if (i0 >= n) return;
        float re[8], im[8];
        if (isbf) {
            const uint4* p = (const uint4*)((const uint32_t*)src + i0);
            uint4 a = p[0], bb = p[1];
            uint32_t x[8] = {a.x, a.y, a.z, a.w, bb.x, bb.y, bb.z, bb.w};
#pragma unroll
            for (int j = 0; j < 8; ++j) { re[j] = bf2f(x[j] & 0xffffu); im[j] = bf2f(x[j] >> 16); }
        } else {
            const float4* p = (const float4*)((const float*)src + 2 * (size_t)i0);
            float4 f[4] = {p[0], p[1], p[2], p[3]};
#pragma unroll
            for (int j = 0; j < 4; ++j) {
                re[2 * j]     = f[j].x; im[2 * j]     = f[j].y;
                re[2 * j + 1] = f[j].z; im[2 * j + 1] = f[j].w;
            }
        }
        const float s = isQ ? SCALE : 1.0f;   // exact pow2 scale for Q
        union { uint16_t u[8]; uint4 v; } orr, oii;
#pragma unroll
        for (int j = 0; j < 8; ++j) {
            orr.u[j] = (uint16_t)f2bf(re[j] * s);
            oii.u[j] = (uint16_t)f2bf(im[j] * s);
        }
        uint16_t* dr = isQ ? Qr : Kr;
        uint16_t* di = isQ ? Qi : Ki;
        *(uint4*)(dr + i0) = orr.v;
        *(uint4*)(di + i0) = oii.v;
        return;
    }

    // ---- V transpose part ----
    const int lin  = bid - 2 * NCV;
    const int kIdx = lin % (KLEN / 32);
    const int rest = lin / (KLEN / 32);
    const int vIdx = rest % (VDIM / 32);
    const int b    = rest / (VDIM / 32);
    const int k0   = kIdx * 32;
    const int v0   = vIdx * 32;
    const int tx = tid & 31, ty = tid >> 5;   // 32 x 8
    const bool isbf = detect_bf((const uint32_t*)vsrc, tid, 256, &scnt);
#pragma unroll
    for (int yy = 0; yy < 4; ++yy) {
        int kl = ty + yy * 8;
        size_t idx = ((size_t)b * KLEN + (k0 + kl)) * VDIM + v0 + tx;
        uint16_t rr, im;
        if (isbf) {
            uint32_t w = ((const uint32_t*)vsrc)[idx];
            rr = (uint16_t)(w & 0xffffu); im = (uint16_t)(w >> 16);
        } else {
            float2 f = ((const float2*)vsrc)[idx];
            rr = (uint16_t)f2bf(f.x); im = (uint16_t)f2bf(f.y);
        }
        tr[kl][tx] = rr;
        ti[kl][tx] = im;
    }
    __syncthreads();
#pragma unroll
    for (int yy = 0; yy < 4; ++yy) {
        int vl = ty + yy * 8;
        size_t o = ((size_t)b * VDIM + (v0 + vl)) * KLEN + k0 + tx;
        vr[o] = tr[tx][vl];
        vi[o] = ti[tx][vl];
    }
}

// ---------- main: split-K complex attention (r7 core) + FUSED combine tail ----------
// r8 post-mortem: five schedules all 84-92us -> r7 core is the stable local
// optimum; the bigger term is the ~90us OUTSIDE this kernel. Fusion: split-K
// partials are PLAIN SUMS (no-max softmax), so combine is done by the LAST
// finishing chunk block per (qt,b) via device-fence + atomic counter --
// deletes the combine launch and keeps the 33MB reduction cache-warm.
template<int NC>
__launch_bounds__(256, 2)
__global__ void cattn_split(const uint16_t* __restrict__ Qr, const uint16_t* __restrict__ Qi,
                            const uint16_t* __restrict__ Kr, const uint16_t* __restrict__ Ki,
                            const uint16_t* __restrict__ VrT, const uint16_t* __restrict__ ViT,
                            float2* __restrict__ Ypart, float* __restrict__ Lpart,
                            int* __restrict__ Cnt, float2* __restrict__ Out) {
    constexpr int CK = KLEN / NC;
    constexpr int NT = CK / 32;
    constexpr int QT = QLEN / 128;               // q-tiles (128 q/block)
    static_assert((NC * BATCH) % 8 == 0, "bijective xcd swizzle");
    constexpr int GPX = (NC * BATCH) / 8;        // (c,b) groups per XCD

    __shared__ __align__(16) uint8_t sK[4][2][4096];   // [buf][r/i][bytes] 32KB
    __shared__ __align__(16) uint8_t sV[4][2][4096];   // 32KB

    const int wave = threadIdx.x >> 6;
    const int lane = threadIdx.x & 63;
    const int r    = lane & 15;
    const int quad = lane >> 4;

    // ---- XCD-aware decode: all q-tiles of a (c,b) group on one XCD ----
    const int lin   = blockIdx.x;
    const int xcd   = lin & 7;
    const int slot  = lin >> 3;                  // 0 .. GPX*QT-1
    const int group = xcd * GPX + slot / QT;
    const int qt    = slot % QT;
    const int b     = group & (BATCH - 1);
    const int c     = group >> 2;
    const int q0    = qt * 128 + wave * 32;

    // Q as B-fragment, two q-halves: lane holds Q[q0+h*16+r][quad*8..+7] (+32)
    bf16x8 aQr0[2], aQr1[2], aQi0[2], aQi1[2], aQn0[2], aQn1[2];
#pragma unroll
    for (int h = 0; h < 2; ++h) {
        const size_t qrow = ((size_t)b * QLEN + q0 + h * 16 + r) * DDIM + quad * 8;
        aQr0[h] = *(const bf16x8*)(Qr + qrow);
        aQr1[h] = *(const bf16x8*)(Qr + qrow + 32);
        aQi0[h] = *(const bf16x8*)(Qi + qrow);
        aQi1[h] = *(const bf16x8*)(Qi + qrow + 32);
        aQn0[h] = neg8(aQi0[h]);   // Si^T = Ki*Qr + Kr*(-Qi)
        aQn1[h] = neg8(aQi1[h]);
    }

    f32x4 Yr[2][4], Yi[2][4];
#pragma unroll
    for (int h = 0; h < 2; ++h)
#pragma unroll
        for (int i = 0; i < 4; ++i) {
            Yr[h][i] = (f32x4){0.f,0.f,0.f,0.f};
            Yi[h][i] = (f32x4){0.f,0.f,0.f,0.f};
        }
    float l_loc[2] = {0.f, 0.f};

    const uint16_t* Krb = Kr  + (size_t)b * KLEN * DDIM;
    const uint16_t* Kib = Ki  + (size_t)b * KLEN * DDIM;
    const uint16_t* Vrb = VrT + (size_t)b * VDIM * KLEN;
    const uint16_t* Vib = ViT + (size_t)b * VDIM * KLEN;

    // ---- staging source: per-lane constant offsets (inverse-swizzled) ----
    const int ksw = ((lane >> 3) << 7) + (((lane & 7) ^ ((lane >> 3) & 7)) << 4);
    const size_t vsw = (size_t)(lane >> 2) * (KLEN * 2) +
                       ((size_t)((lane & 3) ^ ((lane >> 4) & 3)) << 4);

    const uint8_t* stgK = (const uint8_t*)((wave & 1) ? Kib : Krb);
    const uint8_t* stgV = (const uint8_t*)((wave & 1) ? Vib : Vrb);

    auto stage = [&](int buf, int kt) {
        if (wave < 2) {
            const uint8_t* g = stgK + (size_t)kt * 128 + ksw;
            uint8_t* l = &sK[buf][wave & 1][0];
#pragma unroll
            for (int j = 0; j < 4; ++j)
                gload16(g + j * 1024, l + j * 1024);
        } else {
            const uint8_t* g = stgV + (size_t)kt * 2 + vsw;
            uint8_t* l = &sV[buf][wave & 1][0];
#pragma unroll
            for (int j = 0; j < 4; ++j)
                gload16(g + (size_t)j * 16 * (KLEN * 2), l + j * 1024);
        }
    };

    const int kbeg = c * CK;
    static_assert(NT >= 2, "prologue needs >=2 tiles");
    stage(0, kbeg);                       // prologue: tiles 0,1 in flight
    stage(1, kbeg + 32);

    for (int t = 0; t < NT; ++t) {
        const int t2 = t + 2;
        stage(t2 & 3, (t2 < NT) ? kbeg + t2 * 32 : kbeg);   // depth-2 prefetch

        // wait tile t (8 newer loads stay in flight); SINGLE barrier per step.
        asm volatile("s_waitcnt vmcnt(8)\n\ts_barrier" ::: "memory");

        const int cur = t & 3;
        const uint8_t* bKr = &sK[cur][0][0];
        const uint8_t* bKi = &sK[cur][1][0];
        const uint8_t* bVr = &sV[cur][0][0];
        const uint8_t* bVi = &sV[cur][1][0];

        // ---- all fragments up front: 8 K + 8 V ds_read_b128 ----
        bf16x8 kr0[2], kr1[2], ki0[2], ki1[2];
#pragma unroll
        for (int sub = 0; sub < 2; ++sub) {
            const int row = sub * 16 + r;
            const int a1 = row * 128 + ((quad ^ (r & 7)) << 4);
            const int a2 = a1 ^ 64;
            kr0[sub] = *(const bf16x8*)(bKr + a1);
            kr1[sub] = *(const bf16x8*)(bKr + a2);
            ki0[sub] = *(const bf16x8*)(bKi + a1);
            ki1[sub] = *(const bf16x8*)(bKi + a2);
        }
        bf16x8 fvr[4], fvi[4];                      // shared across both halves
#pragma unroll
        for (int vs = 0; vs < 4; ++vs) {
            const int row = vs * 16 + r;
            const int a = row * 64 + ((quad ^ ((r >> 2) & 3)) << 4);
            fvr[vs] = *(const bf16x8*)(bVr + a);
            fvi[vs] = *(const bf16x8*)(bVi + a);
        }

        // ---- QK for BOTH halves first (32 independent MFMAs fill the pipe) ----
        f32x4 Sr[2][2], Si[2][2];
#pragma unroll
        for (int h = 0; h < 2; ++h)
#pragma unroll
            for (int sub = 0; sub < 2; ++sub) {
                f32x4 cc = (f32x4){0.f,0.f,0.f,0.f};
                cc = MFMA16(kr0[sub], aQr0[h], cc);
                cc = MFMA16(kr1[sub], aQr1[h], cc);
                cc = MFMA16(ki0[sub], aQi0[h], cc);
                cc = MFMA16(ki1[sub], aQi1[h], cc);
                Sr[h][sub] = cc;
                f32x4 dd = (f32x4){0.f,0.f,0.f,0.f};
                dd = MFMA16(ki0[sub], aQr0[h], dd);
                dd = MFMA16(ki1[sub], aQr1[h], dd);
                dd = MFMA16(kr0[sub], aQn0[h], dd);
                dd = MFMA16(kr1[sub], aQn1[h], dd);
                Si[h][sub] = dd;
            }

        // ---- per half: softmax (VALU) then PV (MFMA) ----
#pragma unroll
        for (int h = 0; h < 2; ++h) {
            float pr[2][4], pi[2][4];
#pragma unroll
            for (int s = 0; s < 2; ++s)
#pragma unroll
                for (int g = 0; g < 4; ++g) {
                    float sr = Sr[h][s][g], si = Si[h][s][g];
                    float x  = fmaf(sr, sr, fmaf(si, si, 1e-20f));
                    float rq = FRSQ(x);
                    float n  = x * rq;                 // |S|
                    float p  = exp2f(n * LOG2E);       // exp(|S|) (|S|<~9)
                    l_loc[h] += p;
                    float w  = p * rq;                 // exp(n)/n
                    pr[s][g] = sr * w;
                    pi[s][g] = si * w;
                }
            uint32_t r0 = cvt_pk_bf16(pr[0][0], pr[0][1]);
            uint32_t r1 = cvt_pk_bf16(pr[0][2], pr[0][3]);
            uint32_t r2 = cvt_pk_bf16(pr[1][0], pr[1][1]);
            uint32_t r3 = cvt_pk_bf16(pr[1][2], pr[1][3]);
            asm("v_permlane32_swap_b32 %0, %1" : "+v"(r0), "+v"(r2));
            asm("v_permlane32_swap_b32 %0, %1" : "+v"(r1), "+v"(r3));
            asm("v_permlane16_swap_b32 %0, %1" : "+v"(r0), "+v"(r2));
            asm("v_permlane16_swap_b32 %0, %1" : "+v"(r1), "+v"(r3));
            uint32_t i0 = cvt_pk_bf16(pi[0][0], pi[0][1]);
            uint32_t i1 = cvt_pk_bf16(pi[0][2], pi[0][3]);
            uint32_t i2 = cvt_pk_bf16(pi[1][0], pi[1][1]);
            uint32_t i3 = cvt_pk_bf16(pi[1][2], pi[1][3]);
            asm("v_permlane32_swap_b32 %0, %1" : "+v"(i0), "+v"(i2));
            asm("v_permlane32_swap_b32 %0, %1" : "+v"(i1), "+v"(i3));
            asm("v_permlane16_swap_b32 %0, %1" : "+v"(i0), "+v"(i2));
            asm("v_permlane16_swap_b32 %0, %1" : "+v"(i1), "+v"(i3));
            bf16x8 aPr = mk8(r0, r1, r2, r3);
            bf16x8 aPi = mk8(i0, i1, i2, i3);
            bf16x8 aPn = mk8(i0 ^ 0x80008000u, i1 ^ 0x80008000u,
                             i2 ^ 0x80008000u, i3 ^ 0x80008000u);
#pragma unroll
            for (int vs = 0; vs < 4; ++vs) {
                Yr[h][vs] = MFMA16(aPr, fvr[vs], Yr[h][vs]);
                Yr[h][vs] = MFMA16(aPn, fvi[vs], Yr[h][vs]);
                Yi[h][vs] = MFMA16(aPr, fvi[vs], Yi[h][vs]);
                Yi[h][vs] = MFMA16(aPi, fvr[vs], Yi[h][vs]);
            }
        }
    }
    asm volatile("s_waitcnt vmcnt(0)" ::: "memory");   // drain wrap-stage DMA

    // ---- deferred l reduction: row q=r spread across the 4 quads ----
#pragma unroll
    for (int h = 0; h < 2; ++h) {
        l_loc[h] += __shfl_xor(l_loc[h], 16);
        l_loc[h] += __shfl_xor(l_loc[h], 32);
    }

    // ---- write un-normalized partials + l ----
    const size_t pbase = (size_t)(c * BATCH + b) * QLEN;
#pragma unroll
    for (int h = 0; h < 2; ++h)
#pragma unroll
        for (int g = 0; g < 4; ++g) {
            int q = q0 + h * 16 + quad * 4 + g;
#pragma unroll
            for (int vs = 0; vs < 4; ++vs) {
                int v = vs * 16 + r;
                Ypart[(pbase + q) * VDIM + v] = make_float2(Yr[h][vs][g], Yi[h][vs][g]);
            }
        }
    if (lane < 16) {
        Lpart[pbase + q0 + lane]      = l_loc[0];
        Lpart[pbase + q0 + 16 + lane] = l_loc[1];
    }

    // ---- fused combine: last-finishing chunk block for (qt,b) reduces ----
    // Release our stores, then count in. Reuse sK[0] head as the block flag
    // (safe: final loop iteration reads buffers (NT-1)&3 and earlier; no wave
    // touches sK[0] bytes 0..3 after the last barrier when NT%4 != 1... NT=32
    // -> final cur=3; sK[0] last read at t=28, all waves past barrier(29+)).
    volatile int* lastFlag = (volatile int*)&sK[0][0][0];
    __threadfence();
    if (threadIdx.x == 0)
        *lastFlag = (atomicAdd(&Cnt[qt * BATCH + b], 1) == NC - 1) ? 1 : 0;
    __syncthreads();
    if (!*lastFlag) return;
    __threadfence();   // acquire: make other chunks' stores visible

    const int v = threadIdx.x & 63;
    for (int ql = (threadIdx.x >> 6); ql < 128; ql += 4) {
        const int q = qt * 128 + ql;
        float L = 0.f, yr = 0.f, yi = 0.f;
#pragma unroll
        for (int cc = 0; cc < NC; ++cc) {
            size_t base = (size_t)(cc * BATCH + b) * QLEN + q;
            L += Lpart[base];
            float2 y = Ypart[base * VDIM + v];
            yr += y.x;
            yi += y.y;
        }
        float inv = 1.0f / L;
        Out[((size_t)b * QLEN + q) * VDIM + v] = make_float2(yr * inv, yi * inv);
    }
}

// ================== fallback (proven round-5 kernel, no workspace) ==================
__device__ __forceinline__ void load8(const void* base, size_t eidx, bool isbf,
                                      bf16x8& re, bf16x8& im) {
    if (isbf) {
        const uint32_t* p = (const uint32_t*)base + eidx;
        uint4 a = ((const uint4*)p)[0];
        uint4 b = ((const uint4*)p)[1];
        uint32_t x[8] = {a.x, a.y, a.z, a.w, b.x, b.y, b.z, b.w};
#pragma unroll
        for (int j = 0; j < 8; ++j) { re[j] = (short)(x[j] & 0xffffu); im[j] = (short)(x[j] >> 16); }
    } else {
        const float4* p = (const float4*)((const float*)base + 2 * eidx);
        float4 f0 = p[0], f1 = p[1], f2 = p[2], f3 = p[3];
        re[0] = f2bf(f0.x); im[0] = f2bf(f0.y); re[1] = f2bf(f0.z); im[1] = f2bf(f0.w);
        re[2] = f2bf(f1.x); im[2] = f2bf(f1.y); re[3] = f2bf(f1.z); im[3] = f2bf(f1.w);
        re[4] = f2bf(f2.x); im[4] = f2bf(f2.y); re[5] = f2bf(f2.z); im[5] = f2bf(f2.w);
        re[6] = f2bf(f3.x); im[6] = f2bf(f3.y); re[7] = f2bf(f3.z); im[7] = f2bf(f3.w);
    }
}
__device__ __forceinline__ void load8_strided(const void* base, size_t ebase, bool isbf,
                                              bf16x8& re, bf16x8& im) {
    if (isbf) {
        const uint32_t* p = (const uint32_t*)base;
#pragma unroll
        for (int j = 0; j < 8; ++j) {
            uint32_t x = p[ebase + (size_t)j * VDIM];
            re[j] = (short)(x & 0xffffu); im[j] = (short)(x >> 16);
        }
    } else {
        const float2* p = (const float2*)base;
#pragma unroll
        for (int j = 0; j < 8; ++j) {
            float2 f = p[ebase + (size_t)j * VDIM];
            re[j] = f2bf(f.x); im[j] = f2bf(f.y);
        }
    }
}

__launch_bounds__(64)
__global__ void cattn_kernel(const void* __restrict__ Qp, const void* __restrict__ Kp,
                             const void* __restrict__ Vp, float2* __restrict__ out) {
    __shared__ __align__(16) uint16_t sPr[16][40];
    __shared__ __align__(16) uint16_t sPi[16][40];
    const int lane = threadIdx.x;
    const int r    = lane & 15;
    const int quad = lane >> 4;
    const int b    = blockIdx.y;
    const int q0   = blockIdx.x * 16;
    const uint32_t* qu = (const uint32_t*)Qp;
    int cnt = 0;
#pragma unroll
    for (int i = 0; i < 16; ++i) {
        uint32_t e = (qu[lane * 16 + i] >> 7) & 0xFFu;
        cnt += (e >= 110u && e <= 135u) ? 1 : 0;
    }
#pragma unroll
    for (int off = 32; off > 0; off >>= 1) cnt += __shfl_xor(cnt, off);
    const bool isbf = cnt > 512;
    bf16x8 aQr0, aQr1, aQi0, aQi1;
    const size_t qrow = ((size_t)b * QLEN + q0 + r) * DDIM;
    load8(Qp, qrow + quad * 8, isbf, aQr0, aQi0);
    load8(Qp, qrow + 32 + quad * 8, isbf, aQr1, aQi1);
    const bf16x8 aQn0 = neg8(aQi0);
    const bf16x8 aQn1 = neg8(aQi1);
    f32x4 Yr[4], Yi[4];
#pragma unroll
    for (int i = 0; i < 4; ++i) { Yr[i] = (f32x4){0.f,0.f,0.f,0.f}; Yi[i] = (f32x4){0.f,0.f,0.f,0.f}; }
    float m_run[4] = {0.f, 0.f, 0.f, 0.f};
    float l_run[4] = {0.f, 0.f, 0.f, 0.f};
    const size_t kbase = (size_t)b * KLEN * DDIM;
    const size_t vbase = (size_t)b * KLEN * VDIM;
    for (int kt = 0; kt < KLEN; kt += 32) {
        f32x4 Sr[2], Si[2];
#pragma unroll
        for (int sub = 0; sub < 2; ++sub) {
            size_t krow = kbase + (size_t)(kt + sub * 16 + r) * DDIM;
            bf16x8 kr0, ki0, kr1, ki1;
            load8(Kp, krow + quad * 8, isbf, kr0, ki0);
            load8(Kp, krow + 32 + quad * 8, isbf, kr1, ki1);
            f32x4 c = (f32x4){0.f,0.f,0.f,0.f};
            c = MFMA16(aQr0, kr0, c); c = MFMA16(aQr1, kr1, c);
            c = MFMA16(aQi0, ki0, c); c = MFMA16(aQi1, ki1, c);
            Sr[sub] = c;
            f32x4 d = (f32x4){0.f,0.f,0.f,0.f};
            d = MFMA16(aQr0, ki0, d); d = MFMA16(aQr1, ki1, d);
            d = MFMA16(aQn0, kr0, d); d = MFMA16(aQn1, kr1, d);
            Si[sub] = d;
        }
        float nrm[2][4], tmax[4];
#pragma unroll
        for (int g = 0; g < 4; ++g) {
            float sr0 = Sr[0][g] * 0.125f, si0 = Si[0][g] * 0.125f;
            float sr1 = Sr[1][g] * 0.125f, si1 = Si[1][g] * 0.125f;
            Sr[0][g] = sr0; Si[0][g] = si0; Sr[1][g] = sr1; Si[1][g] = si1;
            nrm[0][g] = sqrtf(sr0 * sr0 + si0 * si0);
            nrm[1][g] = sqrtf(sr1 * sr1 + si1 * si1);
            tmax[g] = fmaxf(nrm[0][g], nrm[1][g]);
        }
#pragma unroll
        for (int off = 1; off < 16; off <<= 1) {
#pragma unroll
            for (int g = 0; g < 4; ++g)
                tmax[g] = fmaxf(tmax[g], __shfl_xor(tmax[g], off));
        }
        float alpha[4], psum[4];
#pragma unroll
        for (int g = 0; g < 4; ++g) {
            float mn = fmaxf(m_run[g], tmax[g]);
            alpha[g] = __expf(m_run[g] - mn);
            m_run[g] = mn;
            float p0 = __expf(nrm[0][g] - mn);
            float p1 = __expf(nrm[1][g] - mn);
            psum[g] = p0 + p1;
            float w0 = p0 / (nrm[0][g] + 1e-9f);
            float w1 = p1 / (nrm[1][g] + 1e-9f);
            int row = quad * 4 + g;
            sPr[row][r]      = (uint16_t)f2bf(Sr[0][g] * w0);
            sPi[row][r]      = (uint16_t)f2bf(Si[0][g] * w0);
            sPr[row][r + 16] = (uint16_t)f2bf(Sr[1][g] * w1);
            sPi[row][r + 16] = (uint16_t)f2bf(Si[1][g] * w1);
        }
#pragma unroll
        for (int off = 1; off < 16; off <<= 1) {
#pragma unroll
            for (int g = 0; g < 4; ++g)
                psum[g] += __shfl_xor(psum[g], off);
        }
#pragma unroll
        for (int g = 0; g < 4; ++g) {
            l_run[g] = l_run[g] * alpha[g] + psum[g];
#pragma unroll
            for (int vs = 0; vs < 4; ++vs) { Yr[vs][g] *= alpha[g]; Yi[vs][g] *= alpha[g]; }
        }
        __syncthreads();
        bf16x8 aPr = *(const bf16x8*)&sPr[r][quad * 8];
        bf16x8 aPi = *(const bf16x8*)&sPi[r][quad * 8];
        bf16x8 aPn = neg8(aPi);
#pragma unroll
        for (int vs = 0; vs < 4; ++vs) {
            size_t ebase = vbase + (size_t)(kt + quad * 8) * VDIM + vs * 16 + r;
            bf16x8 bvr, bvi;
            load8_strided(Vp, ebase, isbf, bvr, bvi);
            Yr[vs] = MFMA16(aPr, bvr, Yr[vs]);
            Yr[vs] = MFMA16(aPn, bvi, Yr[vs]);
            Yi[vs] = MFMA16(aPr, bvi, Yi[vs]);
            Yi[vs] = MFMA16(aPi, bvr, Yi[vs]);
        }
        __syncthreads();
    }
#pragma unroll
    for (int g = 0; g < 4; ++g) {
        float inv = 1.0f / l_run[g];
        int q = q0 + quad * 4 + g;
#pragma unroll
        for (int vs = 0; vs < 4; ++vs) {
            int v = vs * 16 + r;
            out[((size_t)b * QLEN + q) * VDIM + v] = make_float2(Yr[vs][g] * inv, Yi[vs][g] * inv);
        }
    }
}

extern "C" void kernel_launch(void* const* d_in, const int* in_sizes, int n_in,
                              void* d_out, int out_size, void* d_ws, size_t ws_size,
                              hipStream_t stream) {
    (void)in_sizes; (void)n_in; (void)out_size;
    const size_t PL = (size_t)BATCH * QLEN * DDIM;                 // 1,048,576 elems
    const size_t planes_bytes = 6 * PL * sizeof(uint16_t);         // 12,582,912
    constexpr int NCSEL = 4;
    const size_t ypart_bytes = (size_t)NCSEL * BATCH * QLEN * VDIM * sizeof(float2);
    const size_t lpart_bytes = (size_t)NCSEL * BATCH * QLEN * sizeof(float);
    const size_t cnt_bytes   = (size_t)(QLEN / 128) * BATCH * sizeof(int);   // 128 counters

    if (ws_size >= planes_bytes + ypart_bytes + lpart_bytes + cnt_bytes) {
        uint16_t* w  = (uint16_t*)d_ws;
        uint16_t* Qr = w;
        uint16_t* Qi = w + PL;
        uint16_t* Kr = w + 2 * PL;
        uint16_t* Ki = w + 3 * PL;
        uint16_t* Vr = w + 4 * PL;
        uint16_t* Vi = w + 5 * PL;
        float2* Ypart = (float2*)((char*)d_ws + planes_bytes);
        float*  Lpart = (float*)((char*)d_ws + planes_bytes + ypart_bytes);
        int*    Cnt   = (int*)((char*)d_ws + planes_bytes + ypart_bytes + lpart_bytes);

        hipMemsetAsync(Cnt, 0, cnt_bytes, stream);

        const int n = (int)PL;
        const int NCV = n / 2048;                                    // 512
        const int NVT = (KLEN / 32) * (VDIM / 32) * BATCH;           // 1024
        prep_kernel<<<dim3(2 * NCV + NVT), dim3(256), 0, stream>>>(
            d_in[0], d_in[1], d_in[2], Qr, Qi, Kr, Ki, Vr, Vi, n);

        // 512 blocks = (QLEN/128) * NC * BATCH; combine fused into the tail.
        cattn_split<NCSEL><<<dim3((QLEN / 128) * NCSEL * BATCH), dim3(256), 0, stream>>>(
            Qr, Qi, Kr, Ki, Vr, Vi, Ypart, Lpart, Cnt, (float2*)d_out);
    } else {
        cattn_kernel<<<dim3(QLEN / 16, BATCH), dim3(64), 0, stream>>>(
            d_in[0], d_in[1], d_in[2], (float2*)d_out);
    }
}

// Round 11
// 203.141 us; speedup vs baseline: 1.2235x; 1.2235x over previous
//
#include <hip/hip_runtime.h>
#include <stdint.h>

typedef __attribute__((ext_vector_type(8))) short bf16x8;
typedef __attribute__((ext_vector_type(4))) float f32x4;

#define MFMA16(a, b, c) __builtin_amdgcn_mfma_f32_16x16x32_bf16((a), (b), (c), 0, 0, 0)

#if __has_builtin(__builtin_amdgcn_rcpf)
#define FRCP(x) __builtin_amdgcn_rcpf(x)
#else
#define FRCP(x) (1.0f / (x))
#endif
#if __has_builtin(__builtin_amdgcn_sqrtf)
#define FSQRT(x) __builtin_amdgcn_sqrtf(x)
#else
#define FSQRT(x) sqrtf(x)
#endif
#if __has_builtin(__builtin_amdgcn_rsqf)
#define FRSQ(x) __builtin_amdgcn_rsqf(x)
#else
#define FRSQ(x) (1.0f / FSQRT(x))
#endif

static constexpr int BATCH = 4;
static constexpr int QLEN  = 4096;
static constexpr int KLEN  = 4096;
static constexpr int DDIM  = 64;
static constexpr int VDIM  = 64;
static constexpr float SCALE = 0.125f;           // 1/sqrt(64), folded into Q at preprocess
static constexpr float LOG2E = 1.44269504088896340736f;

__device__ __forceinline__ float bf2f(uint32_t h) {
    union { uint32_t u; float f; } v; v.u = h << 16; return v.f;
}
__device__ __forceinline__ short f2bf(float x) {
    union { float f; uint32_t u; } v; v.f = x;
    uint32_t u = v.u;
    return (short)((u + 0x7fffu + ((u >> 16) & 1u)) >> 16);   // RNE
}
__device__ __forceinline__ bf16x8 neg8(bf16x8 x) {
#pragma unroll
    for (int i = 0; i < 8; ++i) x[i] ^= (short)0x8000;
    return x;
}
// v_cvt_pk_bf16_f32: d.lo = bf16(lo), d.hi = bf16(hi). No builtin on gfx950 -> asm.
__device__ __forceinline__ uint32_t cvt_pk_bf16(float lo, float hi) {
    uint32_t d;
    asm("v_cvt_pk_bf16_f32 %0, %1, %2" : "=v"(d) : "v"(lo), "v"(hi));
    return d;
}
__device__ __forceinline__ bf16x8 mk8(uint32_t a, uint32_t b, uint32_t c, uint32_t d) {
    union { uint32_t u[4]; bf16x8 v; } x;
    x.u[0] = a; x.u[1] = b; x.u[2] = c; x.u[3] = d;
    return x.v;
}
// async global->LDS DMA, 16B per lane. LDS dest = uniform base + lane*16;
// global src is PER-LANE. Counts in vmcnt.
__device__ __forceinline__ void gload16(const void* g, void* l) {
    __builtin_amdgcn_global_load_lds(
        (const __attribute__((address_space(1))) uint32_t*)g,
        (__attribute__((address_space(3))) uint32_t*)l, 16, 0, 0);
}

// Block-uniform dtype detect: bf16-packed u32 pairs vs float2 per element.
__device__ __forceinline__ bool detect_bf(const uint32_t* src, int tid, int nthreads, int* scnt) {
    if (tid == 0) *scnt = 0;
    __syncthreads();
    int local = 0;
    for (int i = tid; i < 1024; i += nthreads) {
        uint32_t e = (src[i] >> 7) & 0xFFu;
        local += (e >= 110u && e <= 135u) ? 1 : 0;
    }
    atomicAdd(scnt, local);
    __syncthreads();
    return *scnt > 512;
}

// ---------- fused preprocess: QK conv (8 elems/thread) + V transpose ----------
__global__ void prep_kernel(const void* __restrict__ qsrc, const void* __restrict__ ksrc,
                            const void* __restrict__ vsrc,
                            uint16_t* __restrict__ Qr, uint16_t* __restrict__ Qi,
                            uint16_t* __restrict__ Kr, uint16_t* __restrict__ Ki,
                            uint16_t* __restrict__ vr, uint16_t* __restrict__ vi, int n) {
    __shared__ int scnt;
    __shared__ uint16_t tr[32][33];
    __shared__ uint16_t ti[32][33];
    const int NCV = n / 2048;             // conv blocks per tensor (8 elems/thread)
    const int tid = threadIdx.x;
    int bid = blockIdx.x;

    if (bid < 2 * NCV) {
        const bool isQ = (bid < NCV);
        const void* src = isQ ? qsrc : ksrc;
        const bool isbf = detect_bf((const uint32_t*)src, tid, 256, &scnt);
        const int i0 = ((isQ ? bid : bid - NCV) * 256 + tid) * 8;
        if (i0 >= n) return;
        float re[8], im[8];
        if (isbf) {
            const uint4* p = (const uint4*)((const uint32_t*)src + i0);
            uint4 a = p[0], bb = p[1];
            uint32_t x[8] = {a.x, a.y, a.z, a.w, bb.x, bb.y, bb.z, bb.w};
#pragma unroll
            for (int j = 0; j < 8; ++j) { re[j] = bf2f(x[j] & 0xffffu); im[j] = bf2f(x[j] >> 16); }
        } else {
            const float4* p = (const float4*)((const float*)src + 2 * (size_t)i0);
            float4 f[4] = {p[0], p[1], p[2], p[3]};
#pragma unroll
            for (int j = 0; j < 4; ++j) {
                re[2 * j]     = f[j].x; im[2 * j]     = f[j].y;
                re[2 * j + 1] = f[j].z; im[2 * j + 1] = f[j].w;
            }
        }
        const float s = isQ ? SCALE : 1.0f;   // exact pow2 scale for Q
        union { uint16_t u[8]; uint4 v; } orr, oii;
#pragma unroll
        for (int j = 0; j < 8; ++j) {
            orr.u[j] = (uint16_t)f2bf(re[j] * s);
            oii.u[j] = (uint16_t)f2bf(im[j] * s);
        }
        uint16_t* dr = isQ ? Qr : Kr;
        uint16_t* di = isQ ? Qi : Ki;
        *(uint4*)(dr + i0) = orr.v;
        *(uint4*)(di + i0) = oii.v;
        return;
    }

    // ---- V transpose part ----
    const int lin  = bid - 2 * NCV;
    const int kIdx = lin % (KLEN / 32);
    const int rest = lin / (KLEN / 32);
    const int vIdx = rest % (VDIM / 32);
    const int b    = rest / (VDIM / 32);
    const int k0   = kIdx * 32;
    const int v0   = vIdx * 32;
    const int tx = tid & 31, ty = tid >> 5;   // 32 x 8
    const bool isbf = detect_bf((const uint32_t*)vsrc, tid, 256, &scnt);
#pragma unroll
    for (int yy = 0; yy < 4; ++yy) {
        int kl = ty + yy * 8;
        size_t idx = ((size_t)b * KLEN + (k0 + kl)) * VDIM + v0 + tx;
        uint16_t rr, im;
        if (isbf) {
            uint32_t w = ((const uint32_t*)vsrc)[idx];
            rr = (uint16_t)(w & 0xffffu); im = (uint16_t)(w >> 16);
        } else {
            float2 f = ((const float2*)vsrc)[idx];
            rr = (uint16_t)f2bf(f.x); im = (uint16_t)f2bf(f.y);
        }
        tr[kl][tx] = rr;
        ti[kl][tx] = im;
    }
    __syncthreads();
#pragma unroll
    for (int yy = 0; yy < 4; ++yy) {
        int vl = ty + yy * 8;
        size_t o = ((size_t)b * VDIM + (v0 + vl)) * KLEN + k0 + tx;
        vr[o] = tr[tx][vl];
        vi[o] = ti[tx][vl];
    }
}

// ---------- main: split-K complex attention (r7 core) + FUSED combine tail ----------
// r9 post-mortem: __threadfence() (seq_cst agent) emits buffer_inv -> 512
// L2 invalidations wiped the K/V staging locality (FETCH 12->29MB, 84->196us).
// Fix: RELEASE-ONLY fence via __builtin_amdgcn_fence(release, "agent")
// (buffer_wbl2, no inv), and the last block reads other chunks' partials via
// RELAXED AGENT atomic loads (per-access coherent, no L2 invalidate).
// Core loop byte-identical to r7.
template<int NC>
__launch_bounds__(256, 2)
__global__ void cattn_split(const uint16_t* __restrict__ Qr, const uint16_t* __restrict__ Qi,
                            const uint16_t* __restrict__ Kr, const uint16_t* __restrict__ Ki,
                            const uint16_t* __restrict__ VrT, const uint16_t* __restrict__ ViT,
                            float2* __restrict__ Ypart, float* __restrict__ Lpart,
                            int* __restrict__ Cnt, float2* __restrict__ Out) {
    constexpr int CK = KLEN / NC;
    constexpr int NT = CK / 32;
    constexpr int QT = QLEN / 128;               // q-tiles (128 q/block)
    static_assert((NC * BATCH) % 8 == 0, "bijective xcd swizzle");
    constexpr int GPX = (NC * BATCH) / 8;        // (c,b) groups per XCD

    __shared__ __align__(16) uint8_t sK[4][2][4096];   // [buf][r/i][bytes] 32KB
    __shared__ __align__(16) uint8_t sV[4][2][4096];   // 32KB
    __shared__ int lastFlag;

    const int wave = threadIdx.x >> 6;
    const int lane = threadIdx.x & 63;
    const int r    = lane & 15;
    const int quad = lane >> 4;

    // ---- XCD-aware decode: all q-tiles of a (c,b) group on one XCD ----
    const int lin   = blockIdx.x;
    const int xcd   = lin & 7;
    const int slot  = lin >> 3;                  // 0 .. GPX*QT-1
    const int group = xcd * GPX + slot / QT;
    const int qt    = slot % QT;
    const int b     = group & (BATCH - 1);
    const int c     = group >> 2;
    const int q0    = qt * 128 + wave * 32;

    // Q as B-fragment, two q-halves: lane holds Q[q0+h*16+r][quad*8..+7] (+32)
    bf16x8 aQr0[2], aQr1[2], aQi0[2], aQi1[2], aQn0[2], aQn1[2];
#pragma unroll
    for (int h = 0; h < 2; ++h) {
        const size_t qrow = ((size_t)b * QLEN + q0 + h * 16 + r) * DDIM + quad * 8;
        aQr0[h] = *(const bf16x8*)(Qr + qrow);
        aQr1[h] = *(const bf16x8*)(Qr + qrow + 32);
        aQi0[h] = *(const bf16x8*)(Qi + qrow);
        aQi1[h] = *(const bf16x8*)(Qi + qrow + 32);
        aQn0[h] = neg8(aQi0[h]);   // Si^T = Ki*Qr + Kr*(-Qi)
        aQn1[h] = neg8(aQi1[h]);
    }

    f32x4 Yr[2][4], Yi[2][4];
#pragma unroll
    for (int h = 0; h < 2; ++h)
#pragma unroll
        for (int i = 0; i < 4; ++i) {
            Yr[h][i] = (f32x4){0.f,0.f,0.f,0.f};
            Yi[h][i] = (f32x4){0.f,0.f,0.f,0.f};
        }
    float l_loc[2] = {0.f, 0.f};

    const uint16_t* Krb = Kr  + (size_t)b * KLEN * DDIM;
    const uint16_t* Kib = Ki  + (size_t)b * KLEN * DDIM;
    const uint16_t* Vrb = VrT + (size_t)b * VDIM * KLEN;
    const uint16_t* Vib = ViT + (size_t)b * VDIM * KLEN;

    // ---- staging source: per-lane constant offsets (inverse-swizzled) ----
    const int ksw = ((lane >> 3) << 7) + (((lane & 7) ^ ((lane >> 3) & 7)) << 4);
    const size_t vsw = (size_t)(lane >> 2) * (KLEN * 2) +
                       ((size_t)((lane & 3) ^ ((lane >> 4) & 3)) << 4);

    const uint8_t* stgK = (const uint8_t*)((wave & 1) ? Kib : Krb);
    const uint8_t* stgV = (const uint8_t*)((wave & 1) ? Vib : Vrb);

    auto stage = [&](int buf, int kt) {
        if (wave < 2) {
            const uint8_t* g = stgK + (size_t)kt * 128 + ksw;
            uint8_t* l = &sK[buf][wave & 1][0];
#pragma unroll
            for (int j = 0; j < 4; ++j)
                gload16(g + j * 1024, l + j * 1024);
        } else {
            const uint8_t* g = stgV + (size_t)kt * 2 + vsw;
            uint8_t* l = &sV[buf][wave & 1][0];
#pragma unroll
            for (int j = 0; j < 4; ++j)
                gload16(g + (size_t)j * 16 * (KLEN * 2), l + j * 1024);
        }
    };

    const int kbeg = c * CK;
    static_assert(NT >= 2, "prologue needs >=2 tiles");
    stage(0, kbeg);                       // prologue: tiles 0,1 in flight
    stage(1, kbeg + 32);

    for (int t = 0; t < NT; ++t) {
        const int t2 = t + 2;
        stage(t2 & 3, (t2 < NT) ? kbeg + t2 * 32 : kbeg);   // depth-2 prefetch

        // wait tile t (8 newer loads stay in flight); SINGLE barrier per step.
        asm volatile("s_waitcnt vmcnt(8)\n\ts_barrier" ::: "memory");

        const int cur = t & 3;
        const uint8_t* bKr = &sK[cur][0][0];
        const uint8_t* bKi = &sK[cur][1][0];
        const uint8_t* bVr = &sV[cur][0][0];
        const uint8_t* bVi = &sV[cur][1][0];

        // ---- all fragments up front: 8 K + 8 V ds_read_b128 ----
        bf16x8 kr0[2], kr1[2], ki0[2], ki1[2];
#pragma unroll
        for (int sub = 0; sub < 2; ++sub) {
            const int row = sub * 16 + r;
            const int a1 = row * 128 + ((quad ^ (r & 7)) << 4);
            const int a2 = a1 ^ 64;
            kr0[sub] = *(const bf16x8*)(bKr + a1);
            kr1[sub] = *(const bf16x8*)(bKr + a2);
            ki0[sub] = *(const bf16x8*)(bKi + a1);
            ki1[sub] = *(const bf16x8*)(bKi + a2);
        }
        bf16x8 fvr[4], fvi[4];                      // shared across both halves
#pragma unroll
        for (int vs = 0; vs < 4; ++vs) {
            const int row = vs * 16 + r;
            const int a = row * 64 + ((quad ^ ((r >> 2) & 3)) << 4);
            fvr[vs] = *(const bf16x8*)(bVr + a);
            fvi[vs] = *(const bf16x8*)(bVi + a);
        }

        // ---- QK for BOTH halves first (32 independent MFMAs fill the pipe) ----
        f32x4 Sr[2][2], Si[2][2];
#pragma unroll
        for (int h = 0; h < 2; ++h)
#pragma unroll
            for (int sub = 0; sub < 2; ++sub) {
                f32x4 cc = (f32x4){0.f,0.f,0.f,0.f};
                cc = MFMA16(kr0[sub], aQr0[h], cc);
                cc = MFMA16(kr1[sub], aQr1[h], cc);
                cc = MFMA16(ki0[sub], aQi0[h], cc);
                cc = MFMA16(ki1[sub], aQi1[h], cc);
                Sr[h][sub] = cc;
                f32x4 dd = (f32x4){0.f,0.f,0.f,0.f};
                dd = MFMA16(ki0[sub], aQr0[h], dd);
                dd = MFMA16(ki1[sub], aQr1[h], dd);
                dd = MFMA16(kr0[sub], aQn0[h], dd);
                dd = MFMA16(kr1[sub], aQn1[h], dd);
                Si[h][sub] = dd;
            }

        // ---- per half: softmax (VALU) then PV (MFMA) ----
#pragma unroll
        for (int h = 0; h < 2; ++h) {
            float pr[2][4], pi[2][4];
#pragma unroll
            for (int s = 0; s < 2; ++s)
#pragma unroll
                for (int g = 0; g < 4; ++g) {
                    float sr = Sr[h][s][g], si = Si[h][s][g];
                    float x  = fmaf(sr, sr, fmaf(si, si, 1e-20f));
                    float rq = FRSQ(x);
                    float n  = x * rq;                 // |S|
                    float p  = exp2f(n * LOG2E);       // exp(|S|) (|S|<~9)
                    l_loc[h] += p;
                    float w  = p * rq;                 // exp(n)/n
                    pr[s][g] = sr * w;
                    pi[s][g] = si * w;
                }
            uint32_t r0 = cvt_pk_bf16(pr[0][0], pr[0][1]);
            uint32_t r1 = cvt_pk_bf16(pr[0][2], pr[0][3]);
            uint32_t r2 = cvt_pk_bf16(pr[1][0], pr[1][1]);
            uint32_t r3 = cvt_pk_bf16(pr[1][2], pr[1][3]);
            asm("v_permlane32_swap_b32 %0, %1" : "+v"(r0), "+v"(r2));
            asm("v_permlane32_swap_b32 %0, %1" : "+v"(r1), "+v"(r3));
            asm("v_permlane16_swap_b32 %0, %1" : "+v"(r0), "+v"(r2));
            asm("v_permlane16_swap_b32 %0, %1" : "+v"(r1), "+v"(r3));
            uint32_t i0 = cvt_pk_bf16(pi[0][0], pi[0][1]);
            uint32_t i1 = cvt_pk_bf16(pi[0][2], pi[0][3]);
            uint32_t i2 = cvt_pk_bf16(pi[1][0], pi[1][1]);
            uint32_t i3 = cvt_pk_bf16(pi[1][2], pi[1][3]);
            asm("v_permlane32_swap_b32 %0, %1" : "+v"(i0), "+v"(i2));
            asm("v_permlane32_swap_b32 %0, %1" : "+v"(i1), "+v"(i3));
            asm("v_permlane16_swap_b32 %0, %1" : "+v"(i0), "+v"(i2));
            asm("v_permlane16_swap_b32 %0, %1" : "+v"(i1), "+v"(i3));
            bf16x8 aPr = mk8(r0, r1, r2, r3);
            bf16x8 aPi = mk8(i0, i1, i2, i3);
            bf16x8 aPn = mk8(i0 ^ 0x80008000u, i1 ^ 0x80008000u,
                             i2 ^ 0x80008000u, i3 ^ 0x80008000u);
#pragma unroll
            for (int vs = 0; vs < 4; ++vs) {
                Yr[h][vs] = MFMA16(aPr, fvr[vs], Yr[h][vs]);
                Yr[h][vs] = MFMA16(aPn, fvi[vs], Yr[h][vs]);
                Yi[h][vs] = MFMA16(aPr, fvi[vs], Yi[h][vs]);
                Yi[h][vs] = MFMA16(aPi, fvr[vs], Yi[h][vs]);
            }
        }
    }
    asm volatile("s_waitcnt vmcnt(0)" ::: "memory");   // drain wrap-stage DMA

    // ---- deferred l reduction: row q=r spread across the 4 quads ----
#pragma unroll
    for (int h = 0; h < 2; ++h) {
        l_loc[h] += __shfl_xor(l_loc[h], 16);
        l_loc[h] += __shfl_xor(l_loc[h], 32);
    }

    // ---- write un-normalized partials + l ----
    const size_t pbase = (size_t)(c * BATCH + b) * QLEN;
#pragma unroll
    for (int h = 0; h < 2; ++h)
#pragma unroll
        for (int g = 0; g < 4; ++g) {
            int q = q0 + h * 16 + quad * 4 + g;
#pragma unroll
            for (int vs = 0; vs < 4; ++vs) {
                int v = vs * 16 + r;
                Ypart[(pbase + q) * VDIM + v] = make_float2(Yr[h][vs][g], Yi[h][vs][g]);
            }
        }
    if (lane < 16) {
        Lpart[pbase + q0 + lane]      = l_loc[0];
        Lpart[pbase + q0 + 16 + lane] = l_loc[1];
    }

    // ---- fused combine: last-finishing chunk block for (qt,b) reduces ----
    // RELEASE-ONLY fence: buffer_wbl2 (writeback), NO buffer_inv.
    __builtin_amdgcn_fence(__ATOMIC_RELEASE, "agent");
    if (threadIdx.x == 0)
        lastFlag = (__hip_atomic_fetch_add(&Cnt[qt * BATCH + b], 1,
                       __ATOMIC_RELAXED, __HIP_MEMORY_SCOPE_AGENT) == NC - 1) ? 1 : 0;
    __syncthreads();
    if (!lastFlag) return;

    // Other chunks' partials were wbl2'd to the coherent point before their
    // counter increments; read them with relaxed AGENT atomic loads (L2-bypass
    // per access -- no invalidate, no staging-locality destruction).
    const int v  = threadIdx.x & 63;
    const int w4 = threadIdx.x >> 6;
    for (int ql = w4; ql < 128; ql += 8) {      // 2 q per iteration for ILP
        const int qA = qt * 128 + ql;
        const int qB = qA + 4;
        float LA = 0.f, yrA = 0.f, yiA = 0.f;
        float LB = 0.f, yrB = 0.f, yiB = 0.f;
#pragma unroll
        for (int cc = 0; cc < NC; ++cc) {
            size_t baseA = (size_t)(cc * BATCH + b) * QLEN + qA;
            size_t baseB = (size_t)(cc * BATCH + b) * QLEN + qB;
            union { unsigned long long u; float2 f; } ya, yb;
            ya.u = __hip_atomic_load((const unsigned long long*)&Ypart[baseA * VDIM + v],
                                     __ATOMIC_RELAXED, __HIP_MEMORY_SCOPE_AGENT);
            yb.u = __hip_atomic_load((const unsigned long long*)&Ypart[baseB * VDIM + v],
                                     __ATOMIC_RELAXED, __HIP_MEMORY_SCOPE_AGENT);
            float la = __hip_atomic_load(&Lpart[baseA], __ATOMIC_RELAXED,
                                         __HIP_MEMORY_SCOPE_AGENT);
            float lb = __hip_atomic_load(&Lpart[baseB], __ATOMIC_RELAXED,
                                         __HIP_MEMORY_SCOPE_AGENT);
            LA += la; yrA += ya.f.x; yiA += ya.f.y;
            LB += lb; yrB += yb.f.x; yiB += yb.f.y;
        }
        float invA = 1.0f / LA;
        float invB = 1.0f / LB;
        Out[((size_t)b * QLEN + qA) * VDIM + v] = make_float2(yrA * invA, yiA * invA);
        Out[((size_t)b * QLEN + qB) * VDIM + v] = make_float2(yrB * invB, yiB * invB);
    }
}

// ================== fallback (proven round-5 kernel, no workspace) ==================
__device__ __forceinline__ void load8(const void* base, size_t eidx, bool isbf,
                                      bf16x8& re, bf16x8& im) {
    if (isbf) {
        const uint32_t* p = (const uint32_t*)base + eidx;
        uint4 a = ((const uint4*)p)[0];
        uint4 b = ((const uint4*)p)[1];
        uint32_t x[8] = {a.x, a.y, a.z, a.w, b.x, b.y, b.z, b.w};
#pragma unroll
        for (int j = 0; j < 8; ++j) { re[j] = (short)(x[j] & 0xffffu); im[j] = (short)(x[j] >> 16); }
    } else {
        const float4* p = (const float4*)((const float*)base + 2 * eidx);
        float4 f0 = p[0], f1 = p[1], f2 = p[2], f3 = p[3];
        re[0] = f2bf(f0.x); im[0] = f2bf(f0.y); re[1] = f2bf(f0.z); im[1] = f2bf(f0.w);
        re[2] = f2bf(f1.x); im[2] = f2bf(f1.y); re[3] = f2bf(f1.z); im[3] = f2bf(f1.w);
        re[4] = f2bf(f2.x); im[4] = f2bf(f2.y); re[5] = f2bf(f2.z); im[5] = f2bf(f2.w);
        re[6] = f2bf(f3.x); im[6] = f2bf(f3.y); re[7] = f2bf(f3.z); im[7] = f2bf(f3.w);
    }
}
__device__ __forceinline__ void load8_strided(const void* base, size_t ebase, bool isbf,
                                              bf16x8& re, bf16x8& im) {
    if (isbf) {
        const uint32_t* p = (const uint32_t*)base;
#pragma unroll
        for (int j = 0; j < 8; ++j) {
            uint32_t x = p[ebase + (size_t)j * VDIM];
            re[j] = (short)(x & 0xffffu); im[j] = (short)(x >> 16);
        }
    } else {
        const float2* p = (const float2*)base;
#pragma unroll
        for (int j = 0; j < 8; ++j) {
            float2 f = p[ebase + (size_t)j * VDIM];
            re[j] = f2bf(f.x); im[j] = f2bf(f.y);
        }
    }
}

__launch_bounds__(64)
__global__ void cattn_kernel(const void* __restrict__ Qp, const void* __restrict__ Kp,
                             const void* __restrict__ Vp, float2* __restrict__ out) {
    __shared__ __align__(16) uint16_t sPr[16][40];
    __shared__ __align__(16) uint16_t sPi[16][40];
    const int lane = threadIdx.x;
    const int r    = lane & 15;
    const int quad = lane >> 4;
    const int b    = blockIdx.y;
    const int q0   = blockIdx.x * 16;
    const uint32_t* qu = (const uint32_t*)Qp;
    int cnt = 0;
#pragma unroll
    for (int i = 0; i < 16; ++i) {
        uint32_t e = (qu[lane * 16 + i] >> 7) & 0xFFu;
        cnt += (e >= 110u && e <= 135u) ? 1 : 0;
    }
#pragma unroll
    for (int off = 32; off > 0; off >>= 1) cnt += __shfl_xor(cnt, off);
    const bool isbf = cnt > 512;
    bf16x8 aQr0, aQr1, aQi0, aQi1;
    const size_t qrow = ((size_t)b * QLEN + q0 + r) * DDIM;
    load8(Qp, qrow + quad * 8, isbf, aQr0, aQi0);
    load8(Qp, qrow + 32 + quad * 8, isbf, aQr1, aQi1);
    const bf16x8 aQn0 = neg8(aQi0);
    const bf16x8 aQn1 = neg8(aQi1);
    f32x4 Yr[4], Yi[4];
#pragma unroll
    for (int i = 0; i < 4; ++i) { Yr[i] = (f32x4){0.f,0.f,0.f,0.f}; Yi[i] = (f32x4){0.f,0.f,0.f,0.f}; }
    float m_run[4] = {0.f, 0.f, 0.f, 0.f};
    float l_run[4] = {0.f, 0.f, 0.f, 0.f};
    const size_t kbase = (size_t)b * KLEN * DDIM;
    const size_t vbase = (size_t)b * KLEN * VDIM;
    for (int kt = 0; kt < KLEN; kt += 32) {
        f32x4 Sr[2], Si[2];
#pragma unroll
        for (int sub = 0; sub < 2; ++sub) {
            size_t krow = kbase + (size_t)(kt + sub * 16 + r) * DDIM;
            bf16x8 kr0, ki0, kr1, ki1;
            load8(Kp, krow + quad * 8, isbf, kr0, ki0);
            load8(Kp, krow + 32 + quad * 8, isbf, kr1, ki1);
            f32x4 c = (f32x4){0.f,0.f,0.f,0.f};
            c = MFMA16(aQr0, kr0, c); c = MFMA16(aQr1, kr1, c);
            c = MFMA16(aQi0, ki0, c); c = MFMA16(aQi1, ki1, c);
            Sr[sub] = c;
            f32x4 d = (f32x4){0.f,0.f,0.f,0.f};
            d = MFMA16(aQr0, ki0, d); d = MFMA16(aQr1, ki1, d);
            d = MFMA16(aQn0, kr0, d); d = MFMA16(aQn1, kr1, d);
            Si[sub] = d;
        }
        float nrm[2][4], tmax[4];
#pragma unroll
        for (int g = 0; g < 4; ++g) {
            float sr0 = Sr[0][g] * 0.125f, si0 = Si[0][g] * 0.125f;
            float sr1 = Sr[1][g] * 0.125f, si1 = Si[1][g] * 0.125f;
            Sr[0][g] = sr0; Si[0][g] = si0; Sr[1][g] = sr1; Si[1][g] = si1;
            nrm[0][g] = sqrtf(sr0 * sr0 + si0 * si0);
            nrm[1][g] = sqrtf(sr1 * sr1 + si1 * si1);
            tmax[g] = fmaxf(nrm[0][g], nrm[1][g]);
        }
#pragma unroll
        for (int off = 1; off < 16; off <<= 1) {
#pragma unroll
            for (int g = 0; g < 4; ++g)
                tmax[g] = fmaxf(tmax[g], __shfl_xor(tmax[g], off));
        }
        float alpha[4], psum[4];
#pragma unroll
        for (int g = 0; g < 4; ++g) {
            float mn = fmaxf(m_run[g], tmax[g]);
            alpha[g] = __expf(m_run[g] - mn);
            m_run[g] = mn;
            float p0 = __expf(nrm[0][g] - mn);
            float p1 = __expf(nrm[1][g] - mn);
            psum[g] = p0 + p1;
            float w0 = p0 / (nrm[0][g] + 1e-9f);
            float w1 = p1 / (nrm[1][g] + 1e-9f);
            int row = quad * 4 + g;
            sPr[row][r]      = (uint16_t)f2bf(Sr[0][g] * w0);
            sPi[row][r]      = (uint16_t)f2bf(Si[0][g] * w0);
            sPr[row][r + 16] = (uint16_t)f2bf(Sr[1][g] * w1);
            sPi[row][r + 16] = (uint16_t)f2bf(Si[1][g] * w1);
        }
#pragma unroll
        for (int off = 1; off < 16; off <<= 1) {
#pragma unroll
            for (int g = 0; g < 4; ++g)
                psum[g] += __shfl_xor(psum[g], off);
        }
#pragma unroll
        for (int g = 0; g < 4; ++g) {
            l_run[g] = l_run[g] * alpha[g] + psum[g];
#pragma unroll
            for (int vs = 0; vs < 4; ++vs) { Yr[vs][g] *= alpha[g]; Yi[vs][g] *= alpha[g]; }
        }
        __syncthreads();
        bf16x8 aPr = *(const bf16x8*)&sPr[r][quad * 8];
        bf16x8 aPi = *(const bf16x8*)&sPi[r][quad * 8];
        bf16x8 aPn = neg8(aPi);
#pragma unroll
        for (int vs = 0; vs < 4; ++vs) {
            size_t ebase = vbase + (size_t)(kt + quad * 8) * VDIM + vs * 16 + r;
            bf16x8 bvr, bvi;
            load8_strided(Vp, ebase, isbf, bvr, bvi);
            Yr[vs] = MFMA16(aPr, bvr, Yr[vs]);
            Yr[vs] = MFMA16(aPn, bvi, Yr[vs]);
            Yi[vs] = MFMA16(aPr, bvi, Yi[vs]);
            Yi[vs] = MFMA16(aPi, bvr, Yi[vs]);
        }
        __syncthreads();
    }
#pragma unroll
    for (int g = 0; g < 4; ++g) {
        float inv = 1.0f / l_run[g];
        int q = q0 + quad * 4 + g;
#pragma unroll
        for (int vs = 0; vs < 4; ++vs) {
            int v = vs * 16 + r;
            out[((size_t)b * QLEN + q) * VDIM + v] = make_float2(Yr[vs][g] * inv, Yi[vs][g] * inv);
        }
    }
}

extern "C" void kernel_launch(void* const* d_in, const int* in_sizes, int n_in,
                              void* d_out, int out_size, void* d_ws, size_t ws_size,
                              hipStream_t stream) {
    (void)in_sizes; (void)n_in; (void)out_size;
    const size_t PL = (size_t)BATCH * QLEN * DDIM;                 // 1,048,576 elems
    const size_t planes_bytes = 6 * PL * sizeof(uint16_t);         // 12,582,912
    constexpr int NCSEL = 4;
    const size_t ypart_bytes = (size_t)NCSEL * BATCH * QLEN * VDIM * sizeof(float2);
    const size_t lpart_bytes = (size_t)NCSEL * BATCH * QLEN * sizeof(float);
    const size_t cnt_bytes   = (size_t)(QLEN / 128) * BATCH * sizeof(int);   // 128 counters

    if (ws_size >= planes_bytes + ypart_bytes + lpart_bytes + cnt_bytes) {
        uint16_t* w  = (uint16_t*)d_ws;
        uint16_t* Qr = w;
        uint16_t* Qi = w + PL;
        uint16_t* Kr = w + 2 * PL;
        uint16_t* Ki = w + 3 * PL;
        uint16_t* Vr = w + 4 * PL;
        uint16_t* Vi = w + 5 * PL;
        float2* Ypart = (float2*)((char*)d_ws + planes_bytes);
        float*  Lpart = (float*)((char*)d_ws + planes_bytes + ypart_bytes);
        int*    Cnt   = (int*)((char*)d_ws + planes_bytes + ypart_bytes + lpart_bytes);

        (void)hipMemsetAsync(Cnt, 0, cnt_bytes, stream);

        const int n = (int)PL;
        const int NCV = n / 2048;                                    // 512
        const int NVT = (KLEN / 32) * (VDIM / 32) * BATCH;           // 1024
        prep_kernel<<<dim3(2 * NCV + NVT), dim3(256), 0, stream>>>(
            d_in[0], d_in[1], d_in[2], Qr, Qi, Kr, Ki, Vr, Vi, n);

        // 512 blocks = (QLEN/128) * NC * BATCH; combine fused into the tail.
        cattn_split<NCSEL><<<dim3((QLEN / 128) * NCSEL * BATCH), dim3(256), 0, stream>>>(
            Qr, Qi, Kr, Ki, Vr, Vi, Ypart, Lpart, Cnt, (float2*)d_out);
    } else {
        cattn_kernel<<<dim3(QLEN / 16, BATCH), dim3(64), 0, stream>>>(
            d_in[0], d_in[1], d_in[2], (float2*)d_out);
    }
}

// Round 13
// 161.572 us; speedup vs baseline: 1.5382x; 1.2573x over previous
//
#include <hip/hip_runtime.h>
#include <stdint.h>

typedef __attribute__((ext_vector_type(8))) short bf16x8;
typedef __attribute__((ext_vector_type(4))) float f32x4;

#define MFMA16(a, b, c) __builtin_amdgcn_mfma_f32_16x16x32_bf16((a), (b), (c), 0, 0, 0)

#if __has_builtin(__builtin_amdgcn_rcpf)
#define FRCP(x) __builtin_amdgcn_rcpf(x)
#else
#define FRCP(x) (1.0f / (x))
#endif
#if __has_builtin(__builtin_amdgcn_sqrtf)
#define FSQRT(x) __builtin_amdgcn_sqrtf(x)
#else
#define FSQRT(x) sqrtf(x)
#endif
#if __has_builtin(__builtin_amdgcn_rsqf)
#define FRSQ(x) __builtin_amdgcn_rsqf(x)
#else
#define FRSQ(x) (1.0f / FSQRT(x))
#endif

static constexpr int BATCH = 4;
static constexpr int QLEN  = 4096;
static constexpr int KLEN  = 4096;
static constexpr int DDIM  = 64;
static constexpr int VDIM  = 64;
static constexpr float SCALE = 0.125f;           // 1/sqrt(64), folded into Q at preprocess
static constexpr float LOG2E = 1.44269504088896340736f;

__device__ __forceinline__ float bf2f(uint32_t h) {
    union { uint32_t u; float f; } v; v.u = h << 16; return v.f;
}
__device__ __forceinline__ short f2bf(float x) {
    union { float f; uint32_t u; } v; v.f = x;
    uint32_t u = v.u;
    return (short)((u + 0x7fffu + ((u >> 16) & 1u)) >> 16);   // RNE
}
__device__ __forceinline__ bf16x8 neg8(bf16x8 x) {
#pragma unroll
    for (int i = 0; i < 8; ++i) x[i] ^= (short)0x8000;
    return x;
}
// v_cvt_pk_bf16_f32: d.lo = bf16(lo), d.hi = bf16(hi). No builtin on gfx950 -> asm.
__device__ __forceinline__ uint32_t cvt_pk_bf16(float lo, float hi) {
    uint32_t d;
    asm("v_cvt_pk_bf16_f32 %0, %1, %2" : "=v"(d) : "v"(lo), "v"(hi));
    return d;
}
__device__ __forceinline__ bf16x8 mk8(uint32_t a, uint32_t b, uint32_t c, uint32_t d) {
    union { uint32_t u[4]; bf16x8 v; } x;
    x.u[0] = a; x.u[1] = b; x.u[2] = c; x.u[3] = d;
    return x.v;
}
// async global->LDS DMA, 16B per lane. LDS dest = uniform base + lane*16;
// global src is PER-LANE. Counts in vmcnt.
__device__ __forceinline__ void gload16(const void* g, void* l) {
    __builtin_amdgcn_global_load_lds(
        (const __attribute__((address_space(1))) uint32_t*)g,
        (__attribute__((address_space(3))) uint32_t*)l, 16, 0, 0);
}

// Block-uniform dtype detect: bf16-packed u32 pairs vs float2 per element.
__device__ __forceinline__ bool detect_bf(const uint32_t* src, int tid, int nthreads, int* scnt) {
    if (tid == 0) *scnt = 0;
    __syncthreads();
    int local = 0;
    for (int i = tid; i < 1024; i += nthreads) {
        uint32_t e = (src[i] >> 7) & 0xFFu;
        local += (e >= 110u && e <= 135u) ? 1 : 0;
    }
    atomicAdd(scnt, local);
    __syncthreads();
    return *scnt > 512;
}

// ---------- fused preprocess: QK conv (8 elems/thread) + V transpose ----------
__global__ void prep_kernel(const void* __restrict__ qsrc, const void* __restrict__ ksrc,
                            const void* __restrict__ vsrc,
                            uint16_t* __restrict__ Qr, uint16_t* __restrict__ Qi,
                            uint16_t* __restrict__ Kr, uint16_t* __restrict__ Ki,
                            uint16_t* __restrict__ vr, uint16_t* __restrict__ vi, int n) {
    __shared__ int scnt;
    __shared__ uint16_t tr[32][33];
    __shared__ uint16_t ti[32][33];
    const int NCV = n / 2048;             // conv blocks per tensor (8 elems/thread)
    const int tid = threadIdx.x;
    int bid = blockIdx.x;

    if (bid < 2 * NCV) {
        const bool isQ = (bid < NCV);
        const void* src = isQ ? qsrc : ksrc;
        const bool isbf = detect_bf((const uint32_t*)src, tid, 256, &scnt);
        const int i0 = ((isQ ? bid : bid - NCV) * 256 + tid) * 8;
        if (i0 >= n) return;
        float re[8], im[8];
        if (isbf) {
            const uint4* p = (const uint4*)((const uint32_t*)src + i0);
            uint4 a = p[0], bb = p[1];
            uint32_t x[8] = {a.x, a.y, a.z, a.w, bb.x, bb.y, bb.z, bb.w};
#pragma unroll
            for (int j = 0; j < 8; ++j) { re[j] = bf2f(x[j] & 0xffffu); im[j] = bf2f(x[j] >> 16); }
        } else {
            const float4* p = (const float4*)((const float*)src + 2 * (size_t)i0);
            float4 f[4] = {p[0], p[1], p[2], p[3]};
#pragma unroll
            for (int j = 0; j < 4; ++j) {
                re[2 * j]     = f[j].x; im[2 * j]     = f[j].y;
                re[2 * j + 1] = f[j].z; im[2 * j + 1] = f[j].w;
            }
        }
        const float s = isQ ? SCALE : 1.0f;   // exact pow2 scale for Q
        union { uint16_t u[8]; uint4 v; } orr, oii;
#pragma unroll
        for (int j = 0; j < 8; ++j) {
            orr.u[j] = (uint16_t)f2bf(re[j] * s);
            oii.u[j] = (uint16_t)f2bf(im[j] * s);
        }
        uint16_t* dr = isQ ? Qr : Kr;
        uint16_t* di = isQ ? Qi : Ki;
        *(uint4*)(dr + i0) = orr.v;
        *(uint4*)(di + i0) = oii.v;
        return;
    }

    // ---- V transpose part ----
    const int lin  = bid - 2 * NCV;
    const int kIdx = lin % (KLEN / 32);
    const int rest = lin / (KLEN / 32);
    const int vIdx = rest % (VDIM / 32);
    const int b    = rest / (VDIM / 32);
    const int k0   = kIdx * 32;
    const int v0   = vIdx * 32;
    const int tx = tid & 31, ty = tid >> 5;   // 32 x 8
    const bool isbf = detect_bf((const uint32_t*)vsrc, tid, 256, &scnt);
#pragma unroll
    for (int yy = 0; yy < 4; ++yy) {
        int kl = ty + yy * 8;
        size_t idx = ((size_t)b * KLEN + (k0 + kl)) * VDIM + v0 + tx;
        uint16_t rr, im;
        if (isbf) {
            uint32_t w = ((const uint32_t*)vsrc)[idx];
            rr = (uint16_t)(w & 0xffffu); im = (uint16_t)(w >> 16);
        } else {
            float2 f = ((const float2*)vsrc)[idx];
            rr = (uint16_t)f2bf(f.x); im = (uint16_t)f2bf(f.y);
        }
        tr[kl][tx] = rr;
        ti[kl][tx] = im;
    }
    __syncthreads();
#pragma unroll
    for (int yy = 0; yy < 4; ++yy) {
        int vl = ty + yy * 8;
        size_t o = ((size_t)b * VDIM + (v0 + vl)) * KLEN + k0 + tx;
        vr[o] = tr[tx][vl];
        vi[o] = ti[tx][vl];
    }
}

// ---------- main: split-K complex attention (r7 core, reverted) + T5 setprio ----------
// r11 post-mortem: fused-combine variants (r8-r11) never beat r7's separate
// combine; reverted per the pre-committed falsifier. Single new variable:
// s_setprio(1) around the MFMA clusters (T5) -- 2 independent blocks/CU give
// the wave phase-diversity the mechanism requires; MFMA-phase waves win issue
// arbitration over the other block's softmax-phase waves.
template<int NC>
__launch_bounds__(256, 2)
__global__ void cattn_split(const uint16_t* __restrict__ Qr, const uint16_t* __restrict__ Qi,
                            const uint16_t* __restrict__ Kr, const uint16_t* __restrict__ Ki,
                            const uint16_t* __restrict__ VrT, const uint16_t* __restrict__ ViT,
                            float2* __restrict__ Ypart, float* __restrict__ Lpart) {
    constexpr int CK = KLEN / NC;
    constexpr int NT = CK / 32;
    constexpr int QT = QLEN / 128;               // q-tiles (128 q/block)
    static_assert((NC * BATCH) % 8 == 0, "bijective xcd swizzle");
    constexpr int GPX = (NC * BATCH) / 8;        // (c,b) groups per XCD

    __shared__ __align__(16) uint8_t sK[4][2][4096];   // [buf][r/i][bytes] 32KB
    __shared__ __align__(16) uint8_t sV[4][2][4096];   // 32KB

    const int wave = threadIdx.x >> 6;
    const int lane = threadIdx.x & 63;
    const int r    = lane & 15;
    const int quad = lane >> 4;

    // ---- XCD-aware decode: all q-tiles of a (c,b) group on one XCD ----
    const int lin   = blockIdx.x;
    const int xcd   = lin & 7;
    const int slot  = lin >> 3;                  // 0 .. GPX*QT-1
    const int group = xcd * GPX + slot / QT;
    const int qt    = slot % QT;
    const int b     = group & (BATCH - 1);
    const int c     = group >> 2;
    const int q0    = qt * 128 + wave * 32;

    // Q as B-fragment, two q-halves: lane holds Q[q0+h*16+r][quad*8..+7] (+32)
    bf16x8 aQr0[2], aQr1[2], aQi0[2], aQi1[2], aQn0[2], aQn1[2];
#pragma unroll
    for (int h = 0; h < 2; ++h) {
        const size_t qrow = ((size_t)b * QLEN + q0 + h * 16 + r) * DDIM + quad * 8;
        aQr0[h] = *(const bf16x8*)(Qr + qrow);
        aQr1[h] = *(const bf16x8*)(Qr + qrow + 32);
        aQi0[h] = *(const bf16x8*)(Qi + qrow);
        aQi1[h] = *(const bf16x8*)(Qi + qrow + 32);
        aQn0[h] = neg8(aQi0[h]);   // Si^T = Ki*Qr + Kr*(-Qi)
        aQn1[h] = neg8(aQi1[h]);
    }

    f32x4 Yr[2][4], Yi[2][4];
#pragma unroll
    for (int h = 0; h < 2; ++h)
#pragma unroll
        for (int i = 0; i < 4; ++i) {
            Yr[h][i] = (f32x4){0.f,0.f,0.f,0.f};
            Yi[h][i] = (f32x4){0.f,0.f,0.f,0.f};
        }
    float l_loc[2] = {0.f, 0.f};

    const uint16_t* Krb = Kr  + (size_t)b * KLEN * DDIM;
    const uint16_t* Kib = Ki  + (size_t)b * KLEN * DDIM;
    const uint16_t* Vrb = VrT + (size_t)b * VDIM * KLEN;
    const uint16_t* Vib = ViT + (size_t)b * VDIM * KLEN;

    // ---- staging source: per-lane constant offsets (inverse-swizzled) ----
    const int ksw = ((lane >> 3) << 7) + (((lane & 7) ^ ((lane >> 3) & 7)) << 4);
    const size_t vsw = (size_t)(lane >> 2) * (KLEN * 2) +
                       ((size_t)((lane & 3) ^ ((lane >> 4) & 3)) << 4);

    const uint8_t* stgK = (const uint8_t*)((wave & 1) ? Kib : Krb);
    const uint8_t* stgV = (const uint8_t*)((wave & 1) ? Vib : Vrb);

    auto stage = [&](int buf, int kt) {
        if (wave < 2) {
            const uint8_t* g = stgK + (size_t)kt * 128 + ksw;
            uint8_t* l = &sK[buf][wave & 1][0];
#pragma unroll
            for (int j = 0; j < 4; ++j)
                gload16(g + j * 1024, l + j * 1024);
        } else {
            const uint8_t* g = stgV + (size_t)kt * 2 + vsw;
            uint8_t* l = &sV[buf][wave & 1][0];
#pragma unroll
            for (int j = 0; j < 4; ++j)
                gload16(g + (size_t)j * 16 * (KLEN * 2), l + j * 1024);
        }
    };

    const int kbeg = c * CK;
    static_assert(NT >= 2, "prologue needs >=2 tiles");
    stage(0, kbeg);                       // prologue: tiles 0,1 in flight
    stage(1, kbeg + 32);

    for (int t = 0; t < NT; ++t) {
        const int t2 = t + 2;
        stage(t2 & 3, (t2 < NT) ? kbeg + t2 * 32 : kbeg);   // depth-2 prefetch

        // wait tile t (8 newer loads stay in flight); SINGLE barrier per step.
        asm volatile("s_waitcnt vmcnt(8)\n\ts_barrier" ::: "memory");

        const int cur = t & 3;
        const uint8_t* bKr = &sK[cur][0][0];
        const uint8_t* bKi = &sK[cur][1][0];
        const uint8_t* bVr = &sV[cur][0][0];
        const uint8_t* bVi = &sV[cur][1][0];

        // ---- all fragments up front: 8 K + 8 V ds_read_b128 ----
        bf16x8 kr0[2], kr1[2], ki0[2], ki1[2];
#pragma unroll
        for (int sub = 0; sub < 2; ++sub) {
            const int row = sub * 16 + r;
            const int a1 = row * 128 + ((quad ^ (r & 7)) << 4);
            const int a2 = a1 ^ 64;
            kr0[sub] = *(const bf16x8*)(bKr + a1);
            kr1[sub] = *(const bf16x8*)(bKr + a2);
            ki0[sub] = *(const bf16x8*)(bKi + a1);
            ki1[sub] = *(const bf16x8*)(bKi + a2);
        }
        bf16x8 fvr[4], fvi[4];                      // shared across both halves
#pragma unroll
        for (int vs = 0; vs < 4; ++vs) {
            const int row = vs * 16 + r;
            const int a = row * 64 + ((quad ^ ((r >> 2) & 3)) << 4);
            fvr[vs] = *(const bf16x8*)(bVr + a);
            fvi[vs] = *(const bf16x8*)(bVi + a);
        }

        // ---- QK for BOTH halves first (32 independent MFMAs fill the pipe);
        //      T5: boost priority so MFMA-phase waves win CU arbitration ----
        __builtin_amdgcn_s_setprio(1);
        f32x4 Sr[2][2], Si[2][2];
#pragma unroll
        for (int h = 0; h < 2; ++h)
#pragma unroll
            for (int sub = 0; sub < 2; ++sub) {
                f32x4 cc = (f32x4){0.f,0.f,0.f,0.f};
                cc = MFMA16(kr0[sub], aQr0[h], cc);
                cc = MFMA16(kr1[sub], aQr1[h], cc);
                cc = MFMA16(ki0[sub], aQi0[h], cc);
                cc = MFMA16(ki1[sub], aQi1[h], cc);
                Sr[h][sub] = cc;
                f32x4 dd = (f32x4){0.f,0.f,0.f,0.f};
                dd = MFMA16(ki0[sub], aQr0[h], dd);
                dd = MFMA16(ki1[sub], aQr1[h], dd);
                dd = MFMA16(kr0[sub], aQn0[h], dd);
                dd = MFMA16(kr1[sub], aQn1[h], dd);
                Si[h][sub] = dd;
            }
        __builtin_amdgcn_s_setprio(0);

        // ---- per half: softmax (VALU, prio 0) then PV (MFMA, prio 1) ----
#pragma unroll
        for (int h = 0; h < 2; ++h) {
            float pr[2][4], pi[2][4];
#pragma unroll
            for (int s = 0; s < 2; ++s)
#pragma unroll
                for (int g = 0; g < 4; ++g) {
                    float sr = Sr[h][s][g], si = Si[h][s][g];
                    float x  = fmaf(sr, sr, fmaf(si, si, 1e-20f));
                    float rq = FRSQ(x);
                    float n  = x * rq;                 // |S|
                    float p  = exp2f(n * LOG2E);       // exp(|S|) (|S|<~9)
                    l_loc[h] += p;
                    float w  = p * rq;                 // exp(n)/n
                    pr[s][g] = sr * w;
                    pi[s][g] = si * w;
                }
            uint32_t r0 = cvt_pk_bf16(pr[0][0], pr[0][1]);
            uint32_t r1 = cvt_pk_bf16(pr[0][2], pr[0][3]);
            uint32_t r2 = cvt_pk_bf16(pr[1][0], pr[1][1]);
            uint32_t r3 = cvt_pk_bf16(pr[1][2], pr[1][3]);
            asm("v_permlane32_swap_b32 %0, %1" : "+v"(r0), "+v"(r2));
            asm("v_permlane32_swap_b32 %0, %1" : "+v"(r1), "+v"(r3));
            asm("v_permlane16_swap_b32 %0, %1" : "+v"(r0), "+v"(r2));
            asm("v_permlane16_swap_b32 %0, %1" : "+v"(r1), "+v"(r3));
            uint32_t i0 = cvt_pk_bf16(pi[0][0], pi[0][1]);
            uint32_t i1 = cvt_pk_bf16(pi[0][2], pi[0][3]);
            uint32_t i2 = cvt_pk_bf16(pi[1][0], pi[1][1]);
            uint32_t i3 = cvt_pk_bf16(pi[1][2], pi[1][3]);
            asm("v_permlane32_swap_b32 %0, %1" : "+v"(i0), "+v"(i2));
            asm("v_permlane32_swap_b32 %0, %1" : "+v"(i1), "+v"(i3));
            asm("v_permlane16_swap_b32 %0, %1" : "+v"(i0), "+v"(i2));
            asm("v_permlane16_swap_b32 %0, %1" : "+v"(i1), "+v"(i3));
            bf16x8 aPr = mk8(r0, r1, r2, r3);
            bf16x8 aPi = mk8(i0, i1, i2, i3);
            bf16x8 aPn = mk8(i0 ^ 0x80008000u, i1 ^ 0x80008000u,
                             i2 ^ 0x80008000u, i3 ^ 0x80008000u);
            __builtin_amdgcn_s_setprio(1);
#pragma unroll
            for (int vs = 0; vs < 4; ++vs) {
                Yr[h][vs] = MFMA16(aPr, fvr[vs], Yr[h][vs]);
                Yr[h][vs] = MFMA16(aPn, fvi[vs], Yr[h][vs]);
                Yi[h][vs] = MFMA16(aPr, fvi[vs], Yi[h][vs]);
                Yi[h][vs] = MFMA16(aPi, fvr[vs], Yi[h][vs]);
            }
            __builtin_amdgcn_s_setprio(0);
        }
    }
    asm volatile("s_waitcnt vmcnt(0)" ::: "memory");   // drain wrap-stage DMA

    // ---- deferred l reduction: row q=r spread across the 4 quads ----
#pragma unroll
    for (int h = 0; h < 2; ++h) {
        l_loc[h] += __shfl_xor(l_loc[h], 16);
        l_loc[h] += __shfl_xor(l_loc[h], 32);
    }

    // ---- write un-normalized partials + l ----
    const size_t pbase = (size_t)(c * BATCH + b) * QLEN;
#pragma unroll
    for (int h = 0; h < 2; ++h)
#pragma unroll
        for (int g = 0; g < 4; ++g) {
            int q = q0 + h * 16 + quad * 4 + g;
#pragma unroll
            for (int vs = 0; vs < 4; ++vs) {
                int v = vs * 16 + r;
                Ypart[(pbase + q) * VDIM + v] = make_float2(Yr[h][vs][g], Yi[h][vs][g]);
            }
        }
    if (lane < 16) {
        Lpart[pbase + q0 + lane]      = l_loc[0];
        Lpart[pbase + q0 + 16 + lane] = l_loc[1];
    }
}

// ---------- combine split-K partials (exact: plain sums, no per-chunk max) ----------
template<int NC>
__launch_bounds__(256)
__global__ void combine_kernel(const float2* __restrict__ Ypart, const float* __restrict__ Lpart,
                               float2* __restrict__ out) {
    const int v = threadIdx.x & 63;
    const int q = blockIdx.x * 4 + (threadIdx.x >> 6);
    const int b = blockIdx.y;
    float L = 0.f, yr = 0.f, yi = 0.f;
#pragma unroll
    for (int c = 0; c < NC; ++c) {
        size_t base = (size_t)(c * BATCH + b) * QLEN + q;
        L += Lpart[base];
        float2 y = Ypart[base * VDIM + v];
        yr += y.x;
        yi += y.y;
    }
    float inv = 1.0f / L;
    out[((size_t)b * QLEN + q) * VDIM + v] = make_float2(yr * inv, yi * inv);
}

// ================== fallback (proven round-5 kernel, no workspace) ==================
__device__ __forceinline__ void load8(const void* base, size_t eidx, bool isbf,
                                      bf16x8& re, bf16x8& im) {
    if (isbf) {
        const uint32_t* p = (const uint32_t*)base + eidx;
        uint4 a = ((const uint4*)p)[0];
        uint4 b = ((const uint4*)p)[1];
        uint32_t x[8] = {a.x, a.y, a.z, a.w, b.x, b.y, b.z, b.w};
#pragma unroll
        for (int j = 0; j < 8; ++j) { re[j] = (short)(x[j] & 0xffffu); im[j] = (short)(x[j] >> 16); }
    } else {
        const float4* p = (const float4*)((const float*)base + 2 * eidx);
        float4 f0 = p[0], f1 = p[1], f2 = p[2], f3 = p[3];
        re[0] = f2bf(f0.x); im[0] = f2bf(f0.y); re[1] = f2bf(f0.z); im[1] = f2bf(f0.w);
        re[2] = f2bf(f1.x); im[2] = f2bf(f1.y); re[3] = f2bf(f1.z); im[3] = f2bf(f1.w);
        re[4] = f2bf(f2.x); im[4] = f2bf(f2.y); re[5] = f2bf(f2.z); im[5] = f2bf(f2.w);
        re[6] = f2bf(f3.x); im[6] = f2bf(f3.y); re[7] = f2bf(f3.z); im[7] = f2bf(f3.w);
    }
}
__device__ __forceinline__ void load8_strided(const void* base, size_t ebase, bool isbf,
                                              bf16x8& re, bf16x8& im) {
    if (isbf) {
        const uint32_t* p = (const uint32_t*)base;
#pragma unroll
        for (int j = 0; j < 8; ++j) {
            uint32_t x = p[ebase + (size_t)j * VDIM];
            re[j] = (short)(x & 0xffffu); im[j] = (short)(x >> 16);
        }
    } else {
        const float2* p = (const float2*)base;
#pragma unroll
        for (int j = 0; j < 8; ++j) {
            float2 f = p[ebase + (size_t)j * VDIM];
            re[j] = f2bf(f.x); im[j] = f2bf(f.y);
        }
    }
}

__launch_bounds__(64)
__global__ void cattn_kernel(const void* __restrict__ Qp, const void* __restrict__ Kp,
                             const void* __restrict__ Vp, float2* __restrict__ out) {
    __shared__ __align__(16) uint16_t sPr[16][40];
    __shared__ __align__(16) uint16_t sPi[16][40];
    const int lane = threadIdx.x;
    const int r    = lane & 15;
    const int quad = lane >> 4;
    const int b    = blockIdx.y;
    const int q0   = blockIdx.x * 16;
    const uint32_t* qu = (const uint32_t*)Qp;
    int cnt = 0;
#pragma unroll
    for (int i = 0; i < 16; ++i) {
        uint32_t e = (qu[lane * 16 + i] >> 7) & 0xFFu;
        cnt += (e >= 110u && e <= 135u) ? 1 : 0;
    }
#pragma unroll
    for (int off = 32; off > 0; off >>= 1) cnt += __shfl_xor(cnt, off);
    const bool isbf = cnt > 512;
    bf16x8 aQr0, aQr1, aQi0, aQi1;
    const size_t qrow = ((size_t)b * QLEN + q0 + r) * DDIM;
    load8(Qp, qrow + quad * 8, isbf, aQr0, aQi0);
    load8(Qp, qrow + 32 + quad * 8, isbf, aQr1, aQi1);
    const bf16x8 aQn0 = neg8(aQi0);
    const bf16x8 aQn1 = neg8(aQi1);
    f32x4 Yr[4], Yi[4];
#pragma unroll
    for (int i = 0; i < 4; ++i) { Yr[i] = (f32x4){0.f,0.f,0.f,0.f}; Yi[i] = (f32x4){0.f,0.f,0.f,0.f}; }
    float m_run[4] = {0.f, 0.f, 0.f, 0.f};
    float l_run[4] = {0.f, 0.f, 0.f, 0.f};
    const size_t kbase = (size_t)b * KLEN * DDIM;
    const size_t vbase = (size_t)b * KLEN * VDIM;
    for (int kt = 0; kt < KLEN; kt += 32) {
        f32x4 Sr[2], Si[2];
#pragma unroll
        for (int sub = 0; sub < 2; ++sub) {
            size_t krow = kbase + (size_t)(kt + sub * 16 + r) * DDIM;
            bf16x8 kr0, ki0, kr1, ki1;
            load8(Kp, krow + quad * 8, isbf, kr0, ki0);
            load8(Kp, krow + 32 + quad * 8, isbf, kr1, ki1);
            f32x4 c = (f32x4){0.f,0.f,0.f,0.f};
            c = MFMA16(aQr0, kr0, c); c = MFMA16(aQr1, kr1, c);
            c = MFMA16(aQi0, ki0, c); c = MFMA16(aQi1, ki1, c);
            Sr[sub] = c;
            f32x4 d = (f32x4){0.f,0.f,0.f,0.f};
            d = MFMA16(aQr0, ki0, d); d = MFMA16(aQr1, ki1, d);
            d = MFMA16(aQn0, kr0, d); d = MFMA16(aQn1, kr1, d);
            Si[sub] = d;
        }
        float nrm[2][4], tmax[4];
#pragma unroll
        for (int g = 0; g < 4; ++g) {
            float sr0 = Sr[0][g] * 0.125f, si0 = Si[0][g] * 0.125f;
            float sr1 = Sr[1][g] * 0.125f, si1 = Si[1][g] * 0.125f;
            Sr[0][g] = sr0; Si[0][g] = si0; Sr[1][g] = sr1; Si[1][g] = si1;
            nrm[0][g] = sqrtf(sr0 * sr0 + si0 * si0);
            nrm[1][g] = sqrtf(sr1 * sr1 + si1 * si1);
            tmax[g] = fmaxf(nrm[0][g], nrm[1][g]);
        }
#pragma unroll
        for (int off = 1; off < 16; off <<= 1) {
#pragma unroll
            for (int g = 0; g < 4; ++g)
                tmax[g] = fmaxf(tmax[g], __shfl_xor(tmax[g], off));
        }
        float alpha[4], psum[4];
#pragma unroll
        for (int g = 0; g < 4; ++g) {
            float mn = fmaxf(m_run[g], tmax[g]);
            alpha[g] = __expf(m_run[g] - mn);
            m_run[g] = mn;
            float p0 = __expf(nrm[0][g] - mn);
            float p1 = __expf(nrm[1][g] - mn);
            psum[g] = p0 + p1;
            float w0 = p0 / (nrm[0][g] + 1e-9f);
            float w1 = p1 / (nrm[1][g] + 1e-9f);
            int row = quad * 4 + g;
            sPr[row][r]      = (uint16_t)f2bf(Sr[0][g] * w0);
            sPi[row][r]      = (uint16_t)f2bf(Si[0][g] * w0);
            sPr[row][r + 16] = (uint16_t)f2bf(Sr[1][g] * w1);
            sPi[row][r + 16] = (uint16_t)f2bf(Si[1][g] * w1);
        }
#pragma unroll
        for (int off = 1; off < 16; off <<= 1) {
#pragma unroll
            for (int g = 0; g < 4; ++g)
                psum[g] += __shfl_xor(psum[g], off);
        }
#pragma unroll
        for (int g = 0; g < 4; ++g) {
            l_run[g] = l_run[g] * alpha[g] + psum[g];
#pragma unroll
            for (int vs = 0; vs < 4; ++vs) { Yr[vs][g] *= alpha[g]; Yi[vs][g] *= alpha[g]; }
        }
        __syncthreads();
        bf16x8 aPr = *(const bf16x8*)&sPr[r][quad * 8];
        bf16x8 aPi = *(const bf16x8*)&sPi[r][quad * 8];
        bf16x8 aPn = neg8(aPi);
#pragma unroll
        for (int vs = 0; vs < 4; ++vs) {
            size_t ebase = vbase + (size_t)(kt + quad * 8) * VDIM + vs * 16 + r;
            bf16x8 bvr, bvi;
            load8_strided(Vp, ebase, isbf, bvr, bvi);
            Yr[vs] = MFMA16(aPr, bvr, Yr[vs]);
            Yr[vs] = MFMA16(aPn, bvi, Yr[vs]);
            Yi[vs] = MFMA16(aPr, bvi, Yi[vs]);
            Yi[vs] = MFMA16(aPi, bvr, Yi[vs]);
        }
        __syncthreads();
    }
#pragma unroll
    for (int g = 0; g < 4; ++g) {
        float inv = 1.0f / l_run[g];
        int q = q0 + quad * 4 + g;
#pragma unroll
        for (int vs = 0; vs < 4; ++vs) {
            int v = vs * 16 + r;
            out[((size_t)b * QLEN + q) * VDIM + v] = make_float2(Yr[vs][g] * inv, Yi[vs][g] * inv);
        }
    }
}

extern "C" void kernel_launch(void* const* d_in, const int* in_sizes, int n_in,
                              void* d_out, int out_size, void* d_ws, size_t ws_size,
                              hipStream_t stream) {
    (void)in_sizes; (void)n_in; (void)out_size;
    const size_t PL = (size_t)BATCH * QLEN * DDIM;                 // 1,048,576 elems
    const size_t planes_bytes = 6 * PL * sizeof(uint16_t);         // 12,582,912
    constexpr int NCSEL = 4;
    const size_t ypart_bytes = (size_t)NCSEL * BATCH * QLEN * VDIM * sizeof(float2);
    const size_t lpart_bytes = (size_t)NCSEL * BATCH * QLEN * sizeof(float);

    if (ws_size >= planes_bytes + ypart_bytes + lpart_bytes) {
        uint16_t* w  = (uint16_t*)d_ws;
        uint16_t* Qr = w;
        uint16_t* Qi = w + PL;
        uint16_t* Kr = w + 2 * PL;
        uint16_t* Ki = w + 3 * PL;
        uint16_t* Vr = w + 4 * PL;
        uint16_t* Vi = w + 5 * PL;
        float2* Ypart = (float2*)((char*)d_ws + planes_bytes);
        float*  Lpart = (float*)((char*)d_ws + planes_bytes + ypart_bytes);

        const int n = (int)PL;
        const int NCV = n / 2048;                                    // 512
        const int NVT = (KLEN / 32) * (VDIM / 32) * BATCH;           // 1024
        prep_kernel<<<dim3(2 * NCV + NVT), dim3(256), 0, stream>>>(
            d_in[0], d_in[1], d_in[2], Qr, Qi, Kr, Ki, Vr, Vi, n);

        // 512 blocks = (QLEN/128) * NC * BATCH -> 2 resident/CU
        cattn_split<NCSEL><<<dim3((QLEN / 128) * NCSEL * BATCH), dim3(256), 0, stream>>>(
            Qr, Qi, Kr, Ki, Vr, Vi, Ypart, Lpart);

        combine_kernel<NCSEL><<<dim3(QLEN / 4, BATCH), dim3(256), 0, stream>>>(
            Ypart, Lpart, (float2*)d_out);
    } else {
        cattn_kernel<<<dim3(QLEN / 16, BATCH), dim3(64), 0, stream>>>(
            d_in[0], d_in[1], d_in[2], (float2*)d_out);
    }
}

// Round 14
// 157.631 us; speedup vs baseline: 1.5767x; 1.0250x over previous
//
#include <hip/hip_runtime.h>
#include <stdint.h>

typedef __attribute__((ext_vector_type(8))) short bf16x8;
typedef __attribute__((ext_vector_type(4))) float f32x4;

#define MFMA16(a, b, c) __builtin_amdgcn_mfma_f32_16x16x32_bf16((a), (b), (c), 0, 0, 0)

#if __has_builtin(__builtin_amdgcn_rcpf)
#define FRCP(x) __builtin_amdgcn_rcpf(x)
#else
#define FRCP(x) (1.0f / (x))
#endif
#if __has_builtin(__builtin_amdgcn_sqrtf)
#define FSQRT(x) __builtin_amdgcn_sqrtf(x)
#else
#define FSQRT(x) sqrtf(x)
#endif
#if __has_builtin(__builtin_amdgcn_rsqf)
#define FRSQ(x) __builtin_amdgcn_rsqf(x)
#else
#define FRSQ(x) (1.0f / FSQRT(x))
#endif

static constexpr int BATCH = 4;
static constexpr int QLEN  = 4096;
static constexpr int KLEN  = 4096;
static constexpr int DDIM  = 64;
static constexpr int VDIM  = 64;
static constexpr float SCALE = 0.125f;           // 1/sqrt(64), folded into Q at preprocess
static constexpr float LOG2E = 1.44269504088896340736f;

__device__ __forceinline__ float bf2f(uint32_t h) {
    union { uint32_t u; float f; } v; v.u = h << 16; return v.f;
}
__device__ __forceinline__ short f2bf(float x) {
    union { float f; uint32_t u; } v; v.f = x;
    uint32_t u = v.u;
    return (short)((u + 0x7fffu + ((u >> 16) & 1u)) >> 16);   // RNE
}
__device__ __forceinline__ bf16x8 neg8(bf16x8 x) {
#pragma unroll
    for (int i = 0; i < 8; ++i) x[i] ^= (short)0x8000;
    return x;
}
// v_cvt_pk_bf16_f32: d.lo = bf16(lo), d.hi = bf16(hi). No builtin on gfx950 -> asm.
__device__ __forceinline__ uint32_t cvt_pk_bf16(float lo, float hi) {
    uint32_t d;
    asm("v_cvt_pk_bf16_f32 %0, %1, %2" : "=v"(d) : "v"(lo), "v"(hi));
    return d;
}
__device__ __forceinline__ bf16x8 mk8(uint32_t a, uint32_t b, uint32_t c, uint32_t d) {
    union { uint32_t u[4]; bf16x8 v; } x;
    x.u[0] = a; x.u[1] = b; x.u[2] = c; x.u[3] = d;
    return x.v;
}
// async global->LDS DMA, 16B per lane. LDS dest = uniform base + lane*16;
// global src is PER-LANE. Counts in vmcnt.
__device__ __forceinline__ void gload16(const void* g, void* l) {
    __builtin_amdgcn_global_load_lds(
        (const __attribute__((address_space(1))) uint32_t*)g,
        (__attribute__((address_space(3))) uint32_t*)l, 16, 0, 0);
}

// Block-uniform dtype detect: bf16-packed u32 pairs vs float2 per element.
__device__ __forceinline__ bool detect_bf(const uint32_t* src, int tid, int nthreads, int* scnt) {
    if (tid == 0) *scnt = 0;
    __syncthreads();
    int local = 0;
    for (int i = tid; i < 1024; i += nthreads) {
        uint32_t e = (src[i] >> 7) & 0xFFu;
        local += (e >= 110u && e <= 135u) ? 1 : 0;
    }
    atomicAdd(scnt, local);
    __syncthreads();
    return *scnt > 512;
}

// ---------- fused preprocess: QK conv (8 elems/thread) + V transpose ----------
__global__ void prep_kernel(const void* __restrict__ qsrc, const void* __restrict__ ksrc,
                            const void* __restrict__ vsrc,
                            uint16_t* __restrict__ Qr, uint16_t* __restrict__ Qi,
                            uint16_t* __restrict__ Kr, uint16_t* __restrict__ Ki,
                            uint16_t* __restrict__ vr, uint16_t* __restrict__ vi, int n) {
    __shared__ int scnt;
    __shared__ uint16_t tr[32][33];
    __shared__ uint16_t ti[32][33];
    const int NCV = n / 2048;             // conv blocks per tensor (8 elems/thread)
    const int tid = threadIdx.x;
    int bid = blockIdx.x;

    if (bid < 2 * NCV) {
        const bool isQ = (bid < NCV);
        const void* src = isQ ? qsrc : ksrc;
        const bool isbf = detect_bf((const uint32_t*)src, tid, 256, &scnt);
        const int i0 = ((isQ ? bid : bid - NCV) * 256 + tid) * 8;
        if (i0 >= n) return;
        float re[8], im[8];
        if (isbf) {
            const uint4* p = (const uint4*)((const uint32_t*)src + i0);
            uint4 a = p[0], bb = p[1];
            uint32_t x[8] = {a.x, a.y, a.z, a.w, bb.x, bb.y, bb.z, bb.w};
#pragma unroll
            for (int j = 0; j < 8; ++j) { re[j] = bf2f(x[j] & 0xffffu); im[j] = bf2f(x[j] >> 16); }
        } else {
            const float4* p = (const float4*)((const float*)src + 2 * (size_t)i0);
            float4 f[4] = {p[0], p[1], p[2], p[3]};
#pragma unroll
            for (int j = 0; j < 4; ++j) {
                re[2 * j]     = f[j].x; im[2 * j]     = f[j].y;
                re[2 * j + 1] = f[j].z; im[2 * j + 1] = f[j].w;
            }
        }
        const float s = isQ ? SCALE : 1.0f;   // exact pow2 scale for Q
        union { uint16_t u[8]; uint4 v; } orr, oii;
#pragma unroll
        for (int j = 0; j < 8; ++j) {
            orr.u[j] = (uint16_t)f2bf(re[j] * s);
            oii.u[j] = (uint16_t)f2bf(im[j] * s);
        }
        uint16_t* dr = isQ ? Qr : Kr;
        uint16_t* di = isQ ? Qi : Ki;
        *(uint4*)(dr + i0) = orr.v;
        *(uint4*)(di + i0) = oii.v;
        return;
    }

    // ---- V transpose part ----
    const int lin  = bid - 2 * NCV;
    const int kIdx = lin % (KLEN / 32);
    const int rest = lin / (KLEN / 32);
    const int vIdx = rest % (VDIM / 32);
    const int b    = rest / (VDIM / 32);
    const int k0   = kIdx * 32;
    const int v0   = vIdx * 32;
    const int tx = tid & 31, ty = tid >> 5;   // 32 x 8
    const bool isbf = detect_bf((const uint32_t*)vsrc, tid, 256, &scnt);
#pragma unroll
    for (int yy = 0; yy < 4; ++yy) {
        int kl = ty + yy * 8;
        size_t idx = ((size_t)b * KLEN + (k0 + kl)) * VDIM + v0 + tx;
        uint16_t rr, im;
        if (isbf) {
            uint32_t w = ((const uint32_t*)vsrc)[idx];
            rr = (uint16_t)(w & 0xffffu); im = (uint16_t)(w >> 16);
        } else {
            float2 f = ((const float2*)vsrc)[idx];
            rr = (uint16_t)f2bf(f.x); im = (uint16_t)f2bf(f.y);
        }
        tr[kl][tx] = rr;
        ti[kl][tx] = im;
    }
    __syncthreads();
#pragma unroll
    for (int yy = 0; yy < 4; ++yy) {
        int vl = ty + yy * 8;
        size_t o = ((size_t)b * VDIM + (v0 + vl)) * KLEN + k0 + tx;
        vr[o] = tr[tx][vl];
        vi[o] = ti[tx][vl];
    }
}

// ---------- main: split-K complex attention (r7 core, setprio REMOVED) ----------
// r13 post-mortem: T5 setprio regressed cattn 84.4 -> 92.4us (lockstep
// barrier-convoy structure has no wave phase-diversity; matches m190's GEMM
// null/negative). This is the pure r7 core -- the measured-stable 84.4us
// configuration -- with the vectorized prep kept.
template<int NC>
__launch_bounds__(256, 2)
__global__ void cattn_split(const uint16_t* __restrict__ Qr, const uint16_t* __restrict__ Qi,
                            const uint16_t* __restrict__ Kr, const uint16_t* __restrict__ Ki,
                            const uint16_t* __restrict__ VrT, const uint16_t* __restrict__ ViT,
                            float2* __restrict__ Ypart, float* __restrict__ Lpart) {
    constexpr int CK = KLEN / NC;
    constexpr int NT = CK / 32;
    constexpr int QT = QLEN / 128;               // q-tiles (128 q/block)
    static_assert((NC * BATCH) % 8 == 0, "bijective xcd swizzle");
    constexpr int GPX = (NC * BATCH) / 8;        // (c,b) groups per XCD

    __shared__ __align__(16) uint8_t sK[4][2][4096];   // [buf][r/i][bytes] 32KB
    __shared__ __align__(16) uint8_t sV[4][2][4096];   // 32KB

    const int wave = threadIdx.x >> 6;
    const int lane = threadIdx.x & 63;
    const int r    = lane & 15;
    const int quad = lane >> 4;

    // ---- XCD-aware decode: all q-tiles of a (c,b) group on one XCD ----
    const int lin   = blockIdx.x;
    const int xcd   = lin & 7;
    const int slot  = lin >> 3;                  // 0 .. GPX*QT-1
    const int group = xcd * GPX + slot / QT;
    const int qt    = slot % QT;
    const int b     = group & (BATCH - 1);
    const int c     = group >> 2;
    const int q0    = qt * 128 + wave * 32;

    // Q as B-fragment, two q-halves: lane holds Q[q0+h*16+r][quad*8..+7] (+32)
    bf16x8 aQr0[2], aQr1[2], aQi0[2], aQi1[2], aQn0[2], aQn1[2];
#pragma unroll
    for (int h = 0; h < 2; ++h) {
        const size_t qrow = ((size_t)b * QLEN + q0 + h * 16 + r) * DDIM + quad * 8;
        aQr0[h] = *(const bf16x8*)(Qr + qrow);
        aQr1[h] = *(const bf16x8*)(Qr + qrow + 32);
        aQi0[h] = *(const bf16x8*)(Qi + qrow);
        aQi1[h] = *(const bf16x8*)(Qi + qrow + 32);
        aQn0[h] = neg8(aQi0[h]);   // Si^T = Ki*Qr + Kr*(-Qi)
        aQn1[h] = neg8(aQi1[h]);
    }

    f32x4 Yr[2][4], Yi[2][4];
#pragma unroll
    for (int h = 0; h < 2; ++h)
#pragma unroll
        for (int i = 0; i < 4; ++i) {
            Yr[h][i] = (f32x4){0.f,0.f,0.f,0.f};
            Yi[h][i] = (f32x4){0.f,0.f,0.f,0.f};
        }
    float l_loc[2] = {0.f, 0.f};

    const uint16_t* Krb = Kr  + (size_t)b * KLEN * DDIM;
    const uint16_t* Kib = Ki  + (size_t)b * KLEN * DDIM;
    const uint16_t* Vrb = VrT + (size_t)b * VDIM * KLEN;
    const uint16_t* Vib = ViT + (size_t)b * VDIM * KLEN;

    // ---- staging source: per-lane constant offsets (inverse-swizzled) ----
    const int ksw = ((lane >> 3) << 7) + (((lane & 7) ^ ((lane >> 3) & 7)) << 4);
    const size_t vsw = (size_t)(lane >> 2) * (KLEN * 2) +
                       ((size_t)((lane & 3) ^ ((lane >> 4) & 3)) << 4);

    const uint8_t* stgK = (const uint8_t*)((wave & 1) ? Kib : Krb);
    const uint8_t* stgV = (const uint8_t*)((wave & 1) ? Vib : Vrb);

    auto stage = [&](int buf, int kt) {
        if (wave < 2) {
            const uint8_t* g = stgK + (size_t)kt * 128 + ksw;
            uint8_t* l = &sK[buf][wave & 1][0];
#pragma unroll
            for (int j = 0; j < 4; ++j)
                gload16(g + j * 1024, l + j * 1024);
        } else {
            const uint8_t* g = stgV + (size_t)kt * 2 + vsw;
            uint8_t* l = &sV[buf][wave & 1][0];
#pragma unroll
            for (int j = 0; j < 4; ++j)
                gload16(g + (size_t)j * 16 * (KLEN * 2), l + j * 1024);
        }
    };

    const int kbeg = c * CK;
    static_assert(NT >= 2, "prologue needs >=2 tiles");
    stage(0, kbeg);                       // prologue: tiles 0,1 in flight
    stage(1, kbeg + 32);

    for (int t = 0; t < NT; ++t) {
        const int t2 = t + 2;
        stage(t2 & 3, (t2 < NT) ? kbeg + t2 * 32 : kbeg);   // depth-2 prefetch

        // wait tile t (8 newer loads stay in flight); SINGLE barrier per step.
        asm volatile("s_waitcnt vmcnt(8)\n\ts_barrier" ::: "memory");

        const int cur = t & 3;
        const uint8_t* bKr = &sK[cur][0][0];
        const uint8_t* bKi = &sK[cur][1][0];
        const uint8_t* bVr = &sV[cur][0][0];
        const uint8_t* bVi = &sV[cur][1][0];

        // ---- all fragments up front: 8 K + 8 V ds_read_b128 ----
        bf16x8 kr0[2], kr1[2], ki0[2], ki1[2];
#pragma unroll
        for (int sub = 0; sub < 2; ++sub) {
            const int row = sub * 16 + r;
            const int a1 = row * 128 + ((quad ^ (r & 7)) << 4);
            const int a2 = a1 ^ 64;
            kr0[sub] = *(const bf16x8*)(bKr + a1);
            kr1[sub] = *(const bf16x8*)(bKr + a2);
            ki0[sub] = *(const bf16x8*)(bKi + a1);
            ki1[sub] = *(const bf16x8*)(bKi + a2);
        }
        bf16x8 fvr[4], fvi[4];                      // shared across both halves
#pragma unroll
        for (int vs = 0; vs < 4; ++vs) {
            const int row = vs * 16 + r;
            const int a = row * 64 + ((quad ^ ((r >> 2) & 3)) << 4);
            fvr[vs] = *(const bf16x8*)(bVr + a);
            fvi[vs] = *(const bf16x8*)(bVi + a);
        }

        // ---- QK for BOTH halves first (32 independent MFMAs fill the pipe) ----
        f32x4 Sr[2][2], Si[2][2];
#pragma unroll
        for (int h = 0; h < 2; ++h)
#pragma unroll
            for (int sub = 0; sub < 2; ++sub) {
                f32x4 cc = (f32x4){0.f,0.f,0.f,0.f};
                cc = MFMA16(kr0[sub], aQr0[h], cc);
                cc = MFMA16(kr1[sub], aQr1[h], cc);
                cc = MFMA16(ki0[sub], aQi0[h], cc);
                cc = MFMA16(ki1[sub], aQi1[h], cc);
                Sr[h][sub] = cc;
                f32x4 dd = (f32x4){0.f,0.f,0.f,0.f};
                dd = MFMA16(ki0[sub], aQr0[h], dd);
                dd = MFMA16(ki1[sub], aQr1[h], dd);
                dd = MFMA16(kr0[sub], aQn0[h], dd);
                dd = MFMA16(kr1[sub], aQn1[h], dd);
                Si[h][sub] = dd;
            }

        // ---- per half: softmax (VALU) then PV (MFMA) ----
#pragma unroll
        for (int h = 0; h < 2; ++h) {
            float pr[2][4], pi[2][4];
#pragma unroll
            for (int s = 0; s < 2; ++s)
#pragma unroll
                for (int g = 0; g < 4; ++g) {
                    float sr = Sr[h][s][g], si = Si[h][s][g];
                    float x  = fmaf(sr, sr, fmaf(si, si, 1e-20f));
                    float rq = FRSQ(x);
                    float n  = x * rq;                 // |S|
                    float p  = exp2f(n * LOG2E);       // exp(|S|) (|S|<~9)
                    l_loc[h] += p;
                    float w  = p * rq;                 // exp(n)/n
                    pr[s][g] = sr * w;
                    pi[s][g] = si * w;
                }
            uint32_t r0 = cvt_pk_bf16(pr[0][0], pr[0][1]);
            uint32_t r1 = cvt_pk_bf16(pr[0][2], pr[0][3]);
            uint32_t r2 = cvt_pk_bf16(pr[1][0], pr[1][1]);
            uint32_t r3 = cvt_pk_bf16(pr[1][2], pr[1][3]);
            asm("v_permlane32_swap_b32 %0, %1" : "+v"(r0), "+v"(r2));
            asm("v_permlane32_swap_b32 %0, %1" : "+v"(r1), "+v"(r3));
            asm("v_permlane16_swap_b32 %0, %1" : "+v"(r0), "+v"(r2));
            asm("v_permlane16_swap_b32 %0, %1" : "+v"(r1), "+v"(r3));
            uint32_t i0 = cvt_pk_bf16(pi[0][0], pi[0][1]);
            uint32_t i1 = cvt_pk_bf16(pi[0][2], pi[0][3]);
            uint32_t i2 = cvt_pk_bf16(pi[1][0], pi[1][1]);
            uint32_t i3 = cvt_pk_bf16(pi[1][2], pi[1][3]);
            asm("v_permlane32_swap_b32 %0, %1" : "+v"(i0), "+v"(i2));
            asm("v_permlane32_swap_b32 %0, %1" : "+v"(i1), "+v"(i3));
            asm("v_permlane16_swap_b32 %0, %1" : "+v"(i0), "+v"(i2));
            asm("v_permlane16_swap_b32 %0, %1" : "+v"(i1), "+v"(i3));
            bf16x8 aPr = mk8(r0, r1, r2, r3);
            bf16x8 aPi = mk8(i0, i1, i2, i3);
            bf16x8 aPn = mk8(i0 ^ 0x80008000u, i1 ^ 0x80008000u,
                             i2 ^ 0x80008000u, i3 ^ 0x80008000u);
#pragma unroll
            for (int vs = 0; vs < 4; ++vs) {
                Yr[h][vs] = MFMA16(aPr, fvr[vs], Yr[h][vs]);
                Yr[h][vs] = MFMA16(aPn, fvi[vs], Yr[h][vs]);
                Yi[h][vs] = MFMA16(aPr, fvi[vs], Yi[h][vs]);
                Yi[h][vs] = MFMA16(aPi, fvr[vs], Yi[h][vs]);
            }
        }
    }
    asm volatile("s_waitcnt vmcnt(0)" ::: "memory");   // drain wrap-stage DMA

    // ---- deferred l reduction: row q=r spread across the 4 quads ----
#pragma unroll
    for (int h = 0; h < 2; ++h) {
        l_loc[h] += __shfl_xor(l_loc[h], 16);
        l_loc[h] += __shfl_xor(l_loc[h], 32);
    }

    // ---- write un-normalized partials + l ----
    const size_t pbase = (size_t)(c * BATCH + b) * QLEN;
#pragma unroll
    for (int h = 0; h < 2; ++h)
#pragma unroll
        for (int g = 0; g < 4; ++g) {
            int q = q0 + h * 16 + quad * 4 + g;
#pragma unroll
            for (int vs = 0; vs < 4; ++vs) {
                int v = vs * 16 + r;
                Ypart[(pbase + q) * VDIM + v] = make_float2(Yr[h][vs][g], Yi[h][vs][g]);
            }
        }
    if (lane < 16) {
        Lpart[pbase + q0 + lane]      = l_loc[0];
        Lpart[pbase + q0 + 16 + lane] = l_loc[1];
    }
}

// ---------- combine split-K partials (exact: plain sums, no per-chunk max) ----------
template<int NC>
__launch_bounds__(256)
__global__ void combine_kernel(const float2* __restrict__ Ypart, const float* __restrict__ Lpart,
                               float2* __restrict__ out) {
    const int v = threadIdx.x & 63;
    const int q = blockIdx.x * 4 + (threadIdx.x >> 6);
    const int b = blockIdx.y;
    float L = 0.f, yr = 0.f, yi = 0.f;
#pragma unroll
    for (int c = 0; c < NC; ++c) {
        size_t base = (size_t)(c * BATCH + b) * QLEN + q;
        L += Lpart[base];
        float2 y = Ypart[base * VDIM + v];
        yr += y.x;
        yi += y.y;
    }
    float inv = 1.0f / L;
    out[((size_t)b * QLEN + q) * VDIM + v] = make_float2(yr * inv, yi * inv);
}

// ================== fallback (proven round-5 kernel, no workspace) ==================
__device__ __forceinline__ void load8(const void* base, size_t eidx, bool isbf,
                                      bf16x8& re, bf16x8& im) {
    if (isbf) {
        const uint32_t* p = (const uint32_t*)base + eidx;
        uint4 a = ((const uint4*)p)[0];
        uint4 b = ((const uint4*)p)[1];
        uint32_t x[8] = {a.x, a.y, a.z, a.w, b.x, b.y, b.z, b.w};
#pragma unroll
        for (int j = 0; j < 8; ++j) { re[j] = (short)(x[j] & 0xffffu); im[j] = (short)(x[j] >> 16); }
    } else {
        const float4* p = (const float4*)((const float*)base + 2 * eidx);
        float4 f0 = p[0], f1 = p[1], f2 = p[2], f3 = p[3];
        re[0] = f2bf(f0.x); im[0] = f2bf(f0.y); re[1] = f2bf(f0.z); im[1] = f2bf(f0.w);
        re[2] = f2bf(f1.x); im[2] = f2bf(f1.y); re[3] = f2bf(f1.z); im[3] = f2bf(f1.w);
        re[4] = f2bf(f2.x); im[4] = f2bf(f2.y); re[5] = f2bf(f2.z); im[5] = f2bf(f2.w);
        re[6] = f2bf(f3.x); im[6] = f2bf(f3.y); re[7] = f2bf(f3.z); im[7] = f2bf(f3.w);
    }
}
__device__ __forceinline__ void load8_strided(const void* base, size_t ebase, bool isbf,
                                              bf16x8& re, bf16x8& im) {
    if (isbf) {
        const uint32_t* p = (const uint32_t*)base;
#pragma unroll
        for (int j = 0; j < 8; ++j) {
            uint32_t x = p[ebase + (size_t)j * VDIM];
            re[j] = (short)(x & 0xffffu); im[j] = (short)(x >> 16);
        }
    } else {
        const float2* p = (const float2*)base;
#pragma unroll
        for (int j = 0; j < 8; ++j) {
            float2 f = p[ebase + (size_t)j * VDIM];
            re[j] = f2bf(f.x); im[j] = f2bf(f.y);
        }
    }
}

__launch_bounds__(64)
__global__ void cattn_kernel(const void* __restrict__ Qp, const void* __restrict__ Kp,
                             const void* __restrict__ Vp, float2* __restrict__ out) {
    __shared__ __align__(16) uint16_t sPr[16][40];
    __shared__ __align__(16) uint16_t sPi[16][40];
    const int lane = threadIdx.x;
    const int r    = lane & 15;
    const int quad = lane >> 4;
    const int b    = blockIdx.y;
    const int q0   = blockIdx.x * 16;
    const uint32_t* qu = (const uint32_t*)Qp;
    int cnt = 0;
#pragma unroll
    for (int i = 0; i < 16; ++i) {
        uint32_t e = (qu[lane * 16 + i] >> 7) & 0xFFu;
        cnt += (e >= 110u && e <= 135u) ? 1 : 0;
    }
#pragma unroll
    for (int off = 32; off > 0; off >>= 1) cnt += __shfl_xor(cnt, off);
    const bool isbf = cnt > 512;
    bf16x8 aQr0, aQr1, aQi0, aQi1;
    const size_t qrow = ((size_t)b * QLEN + q0 + r) * DDIM;
    load8(Qp, qrow + quad * 8, isbf, aQr0, aQi0);
    load8(Qp, qrow + 32 + quad * 8, isbf, aQr1, aQi1);
    const bf16x8 aQn0 = neg8(aQi0);
    const bf16x8 aQn1 = neg8(aQi1);
    f32x4 Yr[4], Yi[4];
#pragma unroll
    for (int i = 0; i < 4; ++i) { Yr[i] = (f32x4){0.f,0.f,0.f,0.f}; Yi[i] = (f32x4){0.f,0.f,0.f,0.f}; }
    float m_run[4] = {0.f, 0.f, 0.f, 0.f};
    float l_run[4] = {0.f, 0.f, 0.f, 0.f};
    const size_t kbase = (size_t)b * KLEN * DDIM;
    const size_t vbase = (size_t)b * KLEN * VDIM;
    for (int kt = 0; kt < KLEN; kt += 32) {
        f32x4 Sr[2], Si[2];
#pragma unroll
        for (int sub = 0; sub < 2; ++sub) {
            size_t krow = kbase + (size_t)(kt + sub * 16 + r) * DDIM;
            bf16x8 kr0, ki0, kr1, ki1;
            load8(Kp, krow + quad * 8, isbf, kr0, ki0);
            load8(Kp, krow + 32 + quad * 8, isbf, kr1, ki1);
            f32x4 c = (f32x4){0.f,0.f,0.f,0.f};
            c = MFMA16(aQr0, kr0, c); c = MFMA16(aQr1, kr1, c);
            c = MFMA16(aQi0, ki0, c); c = MFMA16(aQi1, ki1, c);
            Sr[sub] = c;
            f32x4 d = (f32x4){0.f,0.f,0.f,0.f};
            d = MFMA16(aQr0, ki0, d); d = MFMA16(aQr1, ki1, d);
            d = MFMA16(aQn0, kr0, d); d = MFMA16(aQn1, kr1, d);
            Si[sub] = d;
        }
        float nrm[2][4], tmax[4];
#pragma unroll
        for (int g = 0; g < 4; ++g) {
            float sr0 = Sr[0][g] * 0.125f, si0 = Si[0][g] * 0.125f;
            float sr1 = Sr[1][g] * 0.125f, si1 = Si[1][g] * 0.125f;
            Sr[0][g] = sr0; Si[0][g] = si0; Sr[1][g] = sr1; Si[1][g] = si1;
            nrm[0][g] = sqrtf(sr0 * sr0 + si0 * si0);
            nrm[1][g] = sqrtf(sr1 * sr1 + si1 * si1);
            tmax[g] = fmaxf(nrm[0][g], nrm[1][g]);
        }
#pragma unroll
        for (int off = 1; off < 16; off <<= 1) {
#pragma unroll
            for (int g = 0; g < 4; ++g)
                tmax[g] = fmaxf(tmax[g], __shfl_xor(tmax[g], off));
        }
        float alpha[4], psum[4];
#pragma unroll
        for (int g = 0; g < 4; ++g) {
            float mn = fmaxf(m_run[g], tmax[g]);
            alpha[g] = __expf(m_run[g] - mn);
            m_run[g] = mn;
            float p0 = __expf(nrm[0][g] - mn);
            float p1 = __expf(nrm[1][g] - mn);
            psum[g] = p0 + p1;
            float w0 = p0 / (nrm[0][g] + 1e-9f);
            float w1 = p1 / (nrm[1][g] + 1e-9f);
            int row = quad * 4 + g;
            sPr[row][r]      = (uint16_t)f2bf(Sr[0][g] * w0);
            sPi[row][r]      = (uint16_t)f2bf(Si[0][g] * w0);
            sPr[row][r + 16] = (uint16_t)f2bf(Sr[1][g] * w1);
            sPi[row][r + 16] = (uint16_t)f2bf(Si[1][g] * w1);
        }
#pragma unroll
        for (int off = 1; off < 16; off <<= 1) {
#pragma unroll
            for (int g = 0; g < 4; ++g)
                psum[g] += __shfl_xor(psum[g], off);
        }
#pragma unroll
        for (int g = 0; g < 4; ++g) {
            l_run[g] = l_run[g] * alpha[g] + psum[g];
#pragma unroll
            for (int vs = 0; vs < 4; ++vs) { Yr[vs][g] *= alpha[g]; Yi[vs][g] *= alpha[g]; }
        }
        __syncthreads();
        bf16x8 aPr = *(const bf16x8*)&sPr[r][quad * 8];
        bf16x8 aPi = *(const bf16x8*)&sPi[r][quad * 8];
        bf16x8 aPn = neg8(aPi);
#pragma unroll
        for (int vs = 0; vs < 4; ++vs) {
            size_t ebase = vbase + (size_t)(kt + quad * 8) * VDIM + vs * 16 + r;
            bf16x8 bvr, bvi;
            load8_strided(Vp, ebase, isbf, bvr, bvi);
            Yr[vs] = MFMA16(aPr, bvr, Yr[vs]);
            Yr[vs] = MFMA16(aPn, bvi, Yr[vs]);
            Yi[vs] = MFMA16(aPr, bvi, Yi[vs]);
            Yi[vs] = MFMA16(aPi, bvr, Yi[vs]);
        }
        __syncthreads();
    }
#pragma unroll
    for (int g = 0; g < 4; ++g) {
        float inv = 1.0f / l_run[g];
        int q = q0 + quad * 4 + g;
#pragma unroll
        for (int vs = 0; vs < 4; ++vs) {
            int v = vs * 16 + r;
            out[((size_t)b * QLEN + q) * VDIM + v] = make_float2(Yr[vs][g] * inv, Yi[vs][g] * inv);
        }
    }
}

extern "C" void kernel_launch(void* const* d_in, const int* in_sizes, int n_in,
                              void* d_out, int out_size, void* d_ws, size_t ws_size,
                              hipStream_t stream) {
    (void)in_sizes; (void)n_in; (void)out_size;
    const size_t PL = (size_t)BATCH * QLEN * DDIM;                 // 1,048,576 elems
    const size_t planes_bytes = 6 * PL * sizeof(uint16_t);         // 12,582,912
    constexpr int NCSEL = 4;
    const size_t ypart_bytes = (size_t)NCSEL * BATCH * QLEN * VDIM * sizeof(float2);
    const size_t lpart_bytes = (size_t)NCSEL * BATCH * QLEN * sizeof(float);

    if (ws_size >= planes_bytes + ypart_bytes + lpart_bytes) {
        uint16_t* w  = (uint16_t*)d_ws;
        uint16_t* Qr = w;
        uint16_t* Qi = w + PL;
        uint16_t* Kr = w + 2 * PL;
        uint16_t* Ki = w + 3 * PL;
        uint16_t* Vr = w + 4 * PL;
        uint16_t* Vi = w + 5 * PL;
        float2* Ypart = (float2*)((char*)d_ws + planes_bytes);
        float*  Lpart = (float*)((char*)d_ws + planes_bytes + ypart_bytes);

        const int n = (int)PL;
        const int NCV = n / 2048;                                    // 512
        const int NVT = (KLEN / 32) * (VDIM / 32) * BATCH;           // 1024
        prep_kernel<<<dim3(2 * NCV + NVT), dim3(256), 0, stream>>>(
            d_in[0], d_in[1], d_in[2], Qr, Qi, Kr, Ki, Vr, Vi, n);

        // 512 blocks = (QLEN/128) * NC * BATCH -> 2 resident/CU
        cattn_split<NCSEL><<<dim3((QLEN / 128) * NCSEL * BATCH), dim3(256), 0, stream>>>(
            Qr, Qi, Kr, Ki, Vr, Vi, Ypart, Lpart);

        combine_kernel<NCSEL><<<dim3(QLEN / 4, BATCH), dim3(256), 0, stream>>>(
            Ypart, Lpart, (float2*)d_out);
    } else {
        cattn_kernel<<<dim3(QLEN / 16, BATCH), dim3(64), 0, stream>>>(
            d_in[0], d_in[1], d_in[2], (float2*)d_out);
    }
}